// Round 1
// baseline (332.833 us; speedup 1.0000x reference)
//
#include <hip/hip_runtime.h>
#include <hip/hip_bf16.h>
#include <stdint.h>

#define NPG 28
#define KDIM 896
#define NOUT 256
#define BM 128
#define BK 32
#define KT (KDIM / BK)   // 28

typedef __attribute__((ext_vector_type(8))) __bf16 bf16x8;
typedef __attribute__((ext_vector_type(8))) ushort us8;
typedef __attribute__((ext_vector_type(4))) float f32x4;

__device__ __forceinline__ ushort f2bf(float v) {
    uint u = __float_as_uint(v);
    return (ushort)((u + 0x7fffu + ((u >> 16) & 1u)) >> 16);
}

__device__ __forceinline__ void gload_lds16(const void* g, void* l) {
    __builtin_amdgcn_global_load_lds(
        (const __attribute__((address_space(1))) void*)(uintptr_t)g,
        (__attribute__((address_space(3))) void*)(uintptr_t)l,
        16, 0, 0);
}

// ---------------- k_agg: atomic-free gather (unchanged) ----------------
__global__ __launch_bounds__(256) void k_agg(
    const float* __restrict__ x, const int* __restrict__ dst,
    const float* __restrict__ f1w,
    float* __restrict__ acc2g, ushort* __restrict__ wt, int nAgg)
{
    __shared__ int   pk[8][32];
    __shared__ float sx[8][32][2];
    __shared__ float t[32][33];

    const int tid = threadIdx.x;

    if ((int)blockIdx.x >= nAgg) {    // fc1_w transpose tiles
        int b = blockIdx.x - nAgg;
        int n0 = (b & 7) * 32, k0 = (b >> 3) * 32;
        int tx = tid & 31, ty = tid >> 5;
#pragma unroll
        for (int q = 0; q < 4; ++q)
            t[ty + q * 8][tx] = f1w[(k0 + ty + q * 8) * NOUT + n0 + tx];
        __syncthreads();
#pragma unroll
        for (int q = 0; q < 4; ++q)
            wt[(long)(n0 + ty + q * 8) * KDIM + k0 + tx] = f2bf(t[tx][ty + q * 8]);
        return;
    }

    const int g = tid >> 5;
    const int j = tid & 31;
    const long gb = ((long)blockIdx.x * 8 + g) * NPG;

    float2 xx = make_float2(0.f, 0.f);
    if (j < NPG) {
        int4 d4 = ((const int4*)dst)[gb + j];
        xx = ((const float2*)x)[gb + j];
        int gbi = (int)gb;
        pk[g][j] = (d4.x - gbi) | ((d4.y - gbi) << 8) |
                   ((d4.z - gbi) << 16) | ((d4.w - gbi) << 24);
    }
    __syncthreads();

    const uint repj = (uint)j * 0x01010101u;
    uint cp0 = 0, cp1 = 0, cp2 = 0, cp3 = 0;
    int cnt = 0;
#pragma unroll
    for (int s4 = 0; s4 < 7; ++s4) {
        int4 pv = *(const int4*)&pk[g][s4 * 4];
#pragma unroll
        for (int r = 0; r < 4; ++r) {
            uint v = ((const uint*)&pv)[r] ^ repj;
            uint zb = ~(((v & 0x7F7F7F7Fu) + 0x7F7F7F7Fu) | v) & 0x80808080u;
            uint c = (uint)__popc(zb);
            cnt += (int)c;
            int s = s4 * 4 + r;
            uint nib = c << ((s & 7) * 4);
            if (s < 8)       cp0 |= nib;
            else if (s < 16) cp1 |= nib;
            else if (s < 24) cp2 |= nib;
            else             cp3 |= nib;
        }
    }

    const float dinv = rsqrtf((float)(1 + cnt));
    const float sx0 = xx.x * dinv, sx1 = xx.y * dinv;
    if (j < NPG) {
        sx[g][j][0] = sx0;
        sx[g][j][1] = sx1;
    }
    __syncthreads();

    float a0 = sx0, a1 = sx1;
#pragma unroll
    for (int s = 0; s < NPG; ++s) {
        float2 sv = *(const float2*)&sx[g][s][0];
        uint cpw = (s < 8) ? cp0 : (s < 16) ? cp1 : (s < 24) ? cp2 : cp3;
        float cf = (float)((cpw >> ((s & 7) * 4)) & 0xFu);
        a0 += cf * sv.x;
        a1 += cf * sv.y;
    }

    if (j < NPG)
        ((float2*)acc2g)[gb + j] = make_float2(a0 * dinv, a1 * dinv);
}

// ---------------- k_gemm helpers (BM=128, BK=32 geometry) ----------------
// Bs stage: 16KB per buffer, 2 gload_lds per thread (wave w covers rows w*32..w*32+31).
// LDS dest is linear; global source granule pre-swizzled so that physical granule
// p = logical_octet ^ ((row>>1)&3)  (conflict-free 64B-row swizzle, both-sides rule).
__device__ __forceinline__ void stage_b2(const char* WtB, ushort* BsX, int kt, int w, int l) {
    const int o = (l & 3) ^ ((l >> 3) & 3);
#pragma unroll
    for (int i = 0; i < 2; ++i) {
        int row = w * 32 + i * 16 + (l >> 2);
        gload_lds16(WtB + (long)row * (KDIM * 2) + kt * 64 + o * 16,
                    (char*)BsX + w * 2048 + i * 1024);
    }
}

// one K-step MFMA cluster: 4x4 16x16x32 tiles per wave
__device__ __forceinline__ void mfma_phase(const ushort* AsX, const ushort* BsX,
                                           f32x4 acc[4][4], int a_off, int b_off) {
    bf16x8 bfr[4];
#pragma unroll
    for (int ni = 0; ni < 4; ++ni)
        bfr[ni] = *(const bf16x8*)(&BsX[b_off + ni * 512]);
#pragma unroll
    for (int mi = 0; mi < 4; ++mi) {
        bf16x8 af = *(const bf16x8*)(&AsX[a_off + mi * 512]);
#pragma unroll
        for (int ni = 0; ni < 4; ++ni)
            acc[mi][ni] = __builtin_amdgcn_mfma_f32_16x16x32_bf16(
                af, bfr[ni], acc[mi][ni], 0, 0, 0);
    }
}

// A-gen write-side: one feature-octet of one row (relu(conv)+bf16 pack)
__device__ __forceinline__ void agen_w(ushort* AsX, float2 av, int awoff,
                                       const float* w0, const float* w1, const float* bb) {
    union { us8 v; uint u[4]; } pk;
#pragma unroll
    for (int k = 0; k < 4; ++k) {
        float e0 = fmaxf(av.x * w0[2 * k]     + av.y * w1[2 * k]     + bb[2 * k],     0.f);
        float e1 = fmaxf(av.x * w0[2 * k + 1] + av.y * w1[2 * k + 1] + bb[2 * k + 1], 0.f);
        __hip_bfloat162 h = __float22bfloat162_rn(make_float2(e0, e1));
        pk.u[k] = *reinterpret_cast<uint*>(&h);
    }
    *(us8*)&AsX[awoff] = pk.v;
}

// ---------------- k_gemm: BM=128, BK=32, 8 waves (2Mx4N), dbuf, 2 blocks/CU ----------------
__global__ __launch_bounds__(512, 4) void k_gemm(
    const float* __restrict__ acc2g, const ushort* __restrict__ Wt,
    const float* __restrict__ cw, const float* __restrict__ cb,
    const float* __restrict__ f1b, const float* __restrict__ f2w,
    const float* __restrict__ f2b, float* __restrict__ out, int Bsz)
{
    __shared__ ushort As0[BM * BK], As1[BM * BK];     // 2 x 8KB
    __shared__ ushort Bs0[NOUT * BK], Bs1[NOUT * BK]; // 2 x 16KB -> 48KB total -> 2 blocks/CU

    const int tid = threadIdx.x;
    const int w = tid >> 6, l = tid & 63;
    const int wM = w >> 2, wN = w & 3;
    const int l15 = l & 15, lhi = l >> 4;
    const long m0 = (long)blockIdx.x * BM;

    // A-gen assignment: one octet (8 features) of one row per thread
    const int ar = tid >> 2;                               // row 0..127
    const int ao = tid & 3;                                // k-octet 0..3
    const int awoff = ar * 32 + ((ao ^ ((ar >> 1) & 3)) * 8);
    float w0[8], w1[8], bb[8];
#pragma unroll
    for (int k = 0; k < 8; ++k) {
        w0[k] = cw[ao * 8 + k]; w1[k] = cw[32 + ao * 8 + k]; bb[k] = cb[ao * 8 + k];
    }

    // swizzled LDS read offsets ((row>>1)&3 == (l15>>1)&3 for 16-aligned row bases)
    const int swz = (lhi ^ ((l15 >> 1) & 3)) * 8;
    const int a_off = (wM * 64 + l15) * 32 + swz;
    const int b_off = (wN * 64 + l15) * 32 + swz;

    const float2* a2 = (const float2*)acc2g;
    const char* WtB = (const char*)Wt;
    const long arow = (m0 + ar) * NPG;

    f32x4 acc[4][4];
#pragma unroll
    for (int mi = 0; mi < 4; ++mi)
#pragma unroll
        for (int ni = 0; ni < 4; ++ni) acc[mi][ni] = (f32x4){0.f, 0.f, 0.f, 0.f};

    // prologue: fill buffers for kt=0
    {
        float2 av0 = a2[arow + 0];
        stage_b2(WtB, Bs0, 0, w, l);
        agen_w(As0, av0, awoff, w0, w1, bb);
    }
    __syncthreads();

    for (int kt = 0; kt < KT; kt += 2) {
        // process buf0 (kt); prefetch kt+1 -> buf1 (issue loads BEFORE mfma, write after)
        float2 av1 = a2[arow + kt + 1];
        stage_b2(WtB, Bs1, kt + 1, w, l);
        __builtin_amdgcn_s_setprio(1);
        mfma_phase(As0, Bs0, acc, a_off, b_off);
        __builtin_amdgcn_s_setprio(0);
        agen_w(As1, av1, awoff, w0, w1, bb);
        __syncthreads();

        // process buf1 (kt+1); prefetch kt+2 -> buf0
        if (kt + 2 < KT) {
            float2 av2 = a2[arow + kt + 2];
            stage_b2(WtB, Bs0, kt + 2, w, l);
            __builtin_amdgcn_s_setprio(1);
            mfma_phase(As1, Bs1, acc, a_off, b_off);
            __builtin_amdgcn_s_setprio(0);
            agen_w(As0, av2, awoff, w0, w1, bb);
            __syncthreads();
        } else {
            __builtin_amdgcn_s_setprio(1);
            mfma_phase(As1, Bs1, acc, a_off, b_off);
            __builtin_amdgcn_s_setprio(0);
        }
    }

    // ---- fused epilogue: +bias, row L2-norm, FC2, sigmoid/softplus ----
    float b1[4], w20[4], w21[4];
#pragma unroll
    for (int ni = 0; ni < 4; ++ni) {
        int col = wN * 64 + ni * 16 + l15;
        b1[ni] = f1b[col];
        w20[ni] = f2w[col * 2 + 0];
        w21[ni] = f2w[col * 2 + 1];
    }
    float* red    = (float*)As0;     // As0 dead (last read before kt=26 barrier)
    float* red_ss = red;             // [128][4]
    float* red_p0 = red + 512;
    float* red_p1 = red + 1024;
    float* red_rn = red + 1536;      // [128]

#pragma unroll
    for (int mi = 0; mi < 4; ++mi) {
        float ssr[4], p0r[4], p1r[4];
#pragma unroll
        for (int r = 0; r < 4; ++r) { ssr[r] = 0.f; p0r[r] = 0.f; p1r[r] = 0.f; }
#pragma unroll
        for (int ni = 0; ni < 4; ++ni) {
#pragma unroll
            for (int r = 0; r < 4; ++r) {
                float v = acc[mi][ni][r] + b1[ni];
                acc[mi][ni][r] = v;
                ssr[r] += v * v;
                p0r[r] += v * w20[ni];
                p1r[r] += v * w21[ni];
            }
        }
#pragma unroll
        for (int m = 1; m < 16; m <<= 1) {
#pragma unroll
            for (int r = 0; r < 4; ++r) {
                ssr[r] += __shfl_xor(ssr[r], m);
                p0r[r] += __shfl_xor(p0r[r], m);
                p1r[r] += __shfl_xor(p1r[r], m);
            }
        }
        if (l15 == 0) {
            int rowb = wM * 64 + mi * 16 + lhi * 4;
#pragma unroll
            for (int r = 0; r < 4; ++r) {
                red_ss[(rowb + r) * 4 + wN] = ssr[r];
                red_p0[(rowb + r) * 4 + wN] = p0r[r];
                red_p1[(rowb + r) * 4 + wN] = p1r[r];
            }
        }
    }
    __syncthreads();

    if (tid < BM) {
        int row = tid;
        float ss = red_ss[row * 4 + 0] + red_ss[row * 4 + 1] + red_ss[row * 4 + 2] + red_ss[row * 4 + 3];
        float p0 = red_p0[row * 4 + 0] + red_p0[row * 4 + 1] + red_p0[row * 4 + 2] + red_p0[row * 4 + 3];
        float p1 = red_p1[row * 4 + 0] + red_p1[row * 4 + 1] + red_p1[row * 4 + 2] + red_p1[row * 4 + 3];
        float rn = 1.0f / fmaxf(sqrtf(ss), 1e-12f);
        float x0 = p0 * rn + f2b[0];
        float x1 = p1 * rn + f2b[1];
        float mu = 1.0f / (1.0f + expf(-x0));
        float th = (x1 > 0.f) ? (x1 + log1pf(expf(-x1))) : log1pf(expf(x1));
        long gr = m0 + row;
        out[(long)Bsz * NOUT + gr] = mu;
        out[(long)Bsz * NOUT + Bsz + gr] = th;
        red_rn[row] = rn;
    }
    __syncthreads();

#pragma unroll
    for (int mi = 0; mi < 4; ++mi) {
        float rn[4];
#pragma unroll
        for (int r = 0; r < 4; ++r) rn[r] = red_rn[wM * 64 + mi * 16 + lhi * 4 + r];
#pragma unroll
        for (int ni = 0; ni < 4; ++ni) {
#pragma unroll
            for (int r = 0; r < 4; ++r) {
                long row = m0 + wM * 64 + mi * 16 + lhi * 4 + r;
                out[row * NOUT + wN * 64 + ni * 16 + l15] = acc[mi][ni][r] * rn[r];
            }
        }
    }
}

extern "C" void kernel_launch(void* const* d_in, const int* in_sizes, int n_in,
                              void* d_out, int out_size, void* d_ws, size_t ws_size,
                              hipStream_t stream) {
    const float* x   = (const float*)d_in[0];
    const int*   ei  = (const int*)d_in[1];
    const float* cw  = (const float*)d_in[2];
    const float* cb  = (const float*)d_in[3];
    const float* f1w = (const float*)d_in[4];
    const float* f1b = (const float*)d_in[5];
    const float* f2w = (const float*)d_in[6];
    const float* f2b = (const float*)d_in[7];
    float* out = (float*)d_out;

    const int Nn  = in_sizes[0] / 2;       // nodes
    const int Bsz = Nn / NPG;              // graphs
    const int E   = in_sizes[1] / 2;       // edges
    const int* dst = ei + E;

    float*  acc2g = (float*)d_ws;                      // [N][2] f32
    ushort* Wt    = (ushort*)(acc2g + (size_t)Nn * 2); // [256][896] bf16

    const int nAgg = Bsz / 8;                          // 8192 (8 graphs per block)
    const int nTr  = (KDIM / 32) * (NOUT / 32);        // 224

    k_agg<<<nAgg + nTr, 256, 0, stream>>>(x, dst, f1w, acc2g, Wt, nAgg);
    k_gemm<<<Bsz / BM, 512, 0, stream>>>(acc2g, Wt, cw, cb, f1b, f2w, f2b, out, Bsz);
}

// Round 2
// 174.094 us; speedup vs baseline: 1.9118x; 1.9118x over previous
//
#include <hip/hip_runtime.h>
#include <hip/hip_bf16.h>
#include <stdint.h>

#define NPG 28
#define KDIM 896
#define NOUT 256
#define BM 64
#define BK 32
#define KT (KDIM / BK)   // 28

typedef __attribute__((ext_vector_type(8))) __bf16 bf16x8;
typedef __attribute__((ext_vector_type(8))) ushort us8;
typedef __attribute__((ext_vector_type(4))) float f32x4;

__device__ __forceinline__ ushort f2bf(float v) {
    uint u = __float_as_uint(v);
    return (ushort)((u + 0x7fffu + ((u >> 16) & 1u)) >> 16);
}

__device__ __forceinline__ void gload_lds16(const void* g, void* l) {
    __builtin_amdgcn_global_load_lds(
        (const __attribute__((address_space(1))) void*)(uintptr_t)g,
        (__attribute__((address_space(3))) void*)(uintptr_t)l,
        16, 0, 0);
}

// ---------------- k_agg: atomic-free gather (unchanged) ----------------
__global__ __launch_bounds__(256) void k_agg(
    const float* __restrict__ x, const int* __restrict__ dst,
    const float* __restrict__ f1w,
    float* __restrict__ acc2g, ushort* __restrict__ wt, int nAgg)
{
    __shared__ int   pk[8][32];
    __shared__ float sx[8][32][2];
    __shared__ float t[32][33];

    const int tid = threadIdx.x;

    if ((int)blockIdx.x >= nAgg) {    // fc1_w transpose tiles
        int b = blockIdx.x - nAgg;
        int n0 = (b & 7) * 32, k0 = (b >> 3) * 32;
        int tx = tid & 31, ty = tid >> 5;
#pragma unroll
        for (int q = 0; q < 4; ++q)
            t[ty + q * 8][tx] = f1w[(k0 + ty + q * 8) * NOUT + n0 + tx];
        __syncthreads();
#pragma unroll
        for (int q = 0; q < 4; ++q)
            wt[(long)(n0 + ty + q * 8) * KDIM + k0 + tx] = f2bf(t[tx][ty + q * 8]);
        return;
    }

    const int g = tid >> 5;
    const int j = tid & 31;
    const long gb = ((long)blockIdx.x * 8 + g) * NPG;

    float2 xx = make_float2(0.f, 0.f);
    if (j < NPG) {
        int4 d4 = ((const int4*)dst)[gb + j];
        xx = ((const float2*)x)[gb + j];
        int gbi = (int)gb;
        pk[g][j] = (d4.x - gbi) | ((d4.y - gbi) << 8) |
                   ((d4.z - gbi) << 16) | ((d4.w - gbi) << 24);
    }
    __syncthreads();

    const uint repj = (uint)j * 0x01010101u;
    uint cp0 = 0, cp1 = 0, cp2 = 0, cp3 = 0;
    int cnt = 0;
#pragma unroll
    for (int s4 = 0; s4 < 7; ++s4) {
        int4 pv = *(const int4*)&pk[g][s4 * 4];
#pragma unroll
        for (int r = 0; r < 4; ++r) {
            uint v = ((const uint*)&pv)[r] ^ repj;
            uint zb = ~(((v & 0x7F7F7F7Fu) + 0x7F7F7F7Fu) | v) & 0x80808080u;
            uint c = (uint)__popc(zb);
            cnt += (int)c;
            int s = s4 * 4 + r;
            uint nib = c << ((s & 7) * 4);
            if (s < 8)       cp0 |= nib;
            else if (s < 16) cp1 |= nib;
            else if (s < 24) cp2 |= nib;
            else             cp3 |= nib;
        }
    }

    const float dinv = rsqrtf((float)(1 + cnt));
    const float sx0 = xx.x * dinv, sx1 = xx.y * dinv;
    if (j < NPG) {
        sx[g][j][0] = sx0;
        sx[g][j][1] = sx1;
    }
    __syncthreads();

    float a0 = sx0, a1 = sx1;
#pragma unroll
    for (int s = 0; s < NPG; ++s) {
        float2 sv = *(const float2*)&sx[g][s][0];
        uint cpw = (s < 8) ? cp0 : (s < 16) ? cp1 : (s < 24) ? cp2 : cp3;
        float cf = (float)((cpw >> ((s & 7) * 4)) & 0xFu);
        a0 += cf * sv.x;
        a1 += cf * sv.y;
    }

    if (j < NPG)
        ((float2*)acc2g)[gb + j] = make_float2(a0 * dinv, a1 * dinv);
}

// ---------------- k_gemm helpers (BM=64, BN=256, BK=32 geometry) ----------------
// Bs stage: 16KB per buffer, 4 gload_lds per wave-lane set (wave w covers rows w*64..w*64+63).
// LDS dest linear; global source granule pre-swizzled: phys = logical ^ ((row>>1)&3).
__device__ __forceinline__ void stage_b4(const char* WtB, ushort* BsX, int kt, int w, int l) {
    const int o = (l & 3) ^ ((l >> 3) & 3);
#pragma unroll
    for (int i = 0; i < 4; ++i) {
        int row = w * 64 + i * 16 + (l >> 2);
        gload_lds16(WtB + (long)row * (KDIM * 2) + kt * 64 + o * 16,
                    (char*)BsX + w * 4096 + i * 1024);
    }
}

// one K-step MFMA cluster: 4x4 16x16x32 tiles per wave (wave covers 64 rows x 64 cols)
__device__ __forceinline__ void mfma_phase(const ushort* AsX, const ushort* BsX,
                                           f32x4 acc[4][4], int a_off, int b_off) {
    bf16x8 bfr[4];
#pragma unroll
    for (int ni = 0; ni < 4; ++ni)
        bfr[ni] = *(const bf16x8*)(&BsX[b_off + ni * 512]);
#pragma unroll
    for (int mi = 0; mi < 4; ++mi) {
        bf16x8 af = *(const bf16x8*)(&AsX[a_off + mi * 512]);
#pragma unroll
        for (int ni = 0; ni < 4; ++ni)
            acc[mi][ni] = __builtin_amdgcn_mfma_f32_16x16x32_bf16(
                af, bfr[ni], acc[mi][ni], 0, 0, 0);
    }
}

// A-gen write-side: one feature-octet of one row (relu(conv)+bf16 pack).
// Octet is wave-uniform -> w0/w1/bb come from scalar loads (SGPRs).
__device__ __forceinline__ void agen_w(ushort* AsX, float2 av, int awoff,
                                       const float* w0, const float* w1, const float* bb) {
    union { us8 v; uint u[4]; } pk;
#pragma unroll
    for (int k = 0; k < 4; ++k) {
        float e0 = fmaxf(av.x * w0[2 * k]     + av.y * w1[2 * k]     + bb[2 * k],     0.f);
        float e1 = fmaxf(av.x * w0[2 * k + 1] + av.y * w1[2 * k + 1] + bb[2 * k + 1], 0.f);
        __hip_bfloat162 h = __float22bfloat162_rn(make_float2(e0, e1));
        pk.u[k] = *reinterpret_cast<uint*>(&h);
    }
    *(us8*)&AsX[awoff] = pk.v;
}

// ---------------- k_gemm: BM=64, BK=32, 4 waves (1Mx4N), dbuf, target 4 blocks/CU ----------------
__global__ __launch_bounds__(256, 4) void k_gemm(
    const float* __restrict__ acc2g, const ushort* __restrict__ Wt,
    const float* __restrict__ cw, const float* __restrict__ cb,
    const float* __restrict__ f1b, const float* __restrict__ f2w,
    const float* __restrict__ f2b, float* __restrict__ out, int Bsz)
{
    __shared__ ushort As0[BM * BK], As1[BM * BK];     // 2 x 4KB
    __shared__ ushort Bs0[NOUT * BK], Bs1[NOUT * BK]; // 2 x 16KB -> 40KB total

    const int tid = threadIdx.x;
    const int w = tid >> 6, l = tid & 63;
    const int l15 = l & 15, lhi = l >> 4;
    const long m0 = (long)blockIdx.x * BM;

    // A-gen: wave w computes feature-octet w for row l (octet wave-uniform -> SGPR weights)
    const int ao = __builtin_amdgcn_readfirstlane(w);
    const int ar = l;                                    // row 0..63
    const int awoff = ar * 32 + ((ao ^ ((ar >> 1) & 3)) * 8);
    float w0[8], w1[8], bb[8];
#pragma unroll
    for (int k = 0; k < 8; ++k) {
        w0[k] = cw[ao * 8 + k]; w1[k] = cw[32 + ao * 8 + k]; bb[k] = cb[ao * 8 + k];
    }

    // swizzled LDS read offsets ((row>>1)&3 == (l15>>1)&3 for 16-aligned row bases)
    const int swz = (lhi ^ ((l15 >> 1) & 3)) * 8;
    const int a_off = l15 * 32 + swz;                  // + mi*512
    const int b_off = (w * 64 + l15) * 32 + swz;       // + ni*512

    const float2* a2 = (const float2*)acc2g;
    const char* WtB = (const char*)Wt;
    const long arow = (m0 + ar) * NPG;

    f32x4 acc[4][4];
#pragma unroll
    for (int mi = 0; mi < 4; ++mi)
#pragma unroll
        for (int ni = 0; ni < 4; ++ni) acc[mi][ni] = (f32x4){0.f, 0.f, 0.f, 0.f};

    // prologue: fill buffers for kt=0
    {
        float2 av0 = a2[arow + 0];
        stage_b4(WtB, Bs0, 0, w, l);
        agen_w(As0, av0, awoff, w0, w1, bb);
    }
    __syncthreads();

    for (int kt = 0; kt < KT; kt += 2) {
        // process buf0 (kt); prefetch kt+1 -> buf1 (issue loads BEFORE mfma, write after)
        float2 av1 = a2[arow + kt + 1];
        stage_b4(WtB, Bs1, kt + 1, w, l);
        __builtin_amdgcn_s_setprio(1);
        mfma_phase(As0, Bs0, acc, a_off, b_off);
        __builtin_amdgcn_s_setprio(0);
        agen_w(As1, av1, awoff, w0, w1, bb);
        __syncthreads();

        // process buf1 (kt+1); prefetch kt+2 -> buf0
        if (kt + 2 < KT) {
            float2 av2 = a2[arow + kt + 2];
            stage_b4(WtB, Bs0, kt + 2, w, l);
            __builtin_amdgcn_s_setprio(1);
            mfma_phase(As1, Bs1, acc, a_off, b_off);
            __builtin_amdgcn_s_setprio(0);
            agen_w(As0, av2, awoff, w0, w1, bb);
            __syncthreads();
        } else {
            __builtin_amdgcn_s_setprio(1);
            mfma_phase(As1, Bs1, acc, a_off, b_off);
            __builtin_amdgcn_s_setprio(0);
        }
    }

    // ---- fused epilogue: +bias, row L2-norm, FC2, sigmoid/softplus ----
    float b1[4], w20[4], w21[4];
#pragma unroll
    for (int ni = 0; ni < 4; ++ni) {
        int col = w * 64 + ni * 16 + l15;
        b1[ni] = f1b[col];
        w20[ni] = f2w[col * 2 + 0];
        w21[ni] = f2w[col * 2 + 1];
    }
    float* red    = (float*)As0;     // As0 dead after last mid-loop barrier
    float* red_ss = red;             // [64][4]
    float* red_p0 = red + 256;
    float* red_p1 = red + 512;
    float* red_rn = red + 768;       // [64]

#pragma unroll
    for (int mi = 0; mi < 4; ++mi) {
        float ssr[4], p0r[4], p1r[4];
#pragma unroll
        for (int r = 0; r < 4; ++r) { ssr[r] = 0.f; p0r[r] = 0.f; p1r[r] = 0.f; }
#pragma unroll
        for (int ni = 0; ni < 4; ++ni) {
#pragma unroll
            for (int r = 0; r < 4; ++r) {
                float v = acc[mi][ni][r] + b1[ni];
                acc[mi][ni][r] = v;
                ssr[r] += v * v;
                p0r[r] += v * w20[ni];
                p1r[r] += v * w21[ni];
            }
        }
#pragma unroll
        for (int m = 1; m < 16; m <<= 1) {
#pragma unroll
            for (int r = 0; r < 4; ++r) {
                ssr[r] += __shfl_xor(ssr[r], m);
                p0r[r] += __shfl_xor(p0r[r], m);
                p1r[r] += __shfl_xor(p1r[r], m);
            }
        }
        if (l15 == 0) {
            int rowb = mi * 16 + lhi * 4;
#pragma unroll
            for (int r = 0; r < 4; ++r) {
                red_ss[(rowb + r) * 4 + w] = ssr[r];
                red_p0[(rowb + r) * 4 + w] = p0r[r];
                red_p1[(rowb + r) * 4 + w] = p1r[r];
            }
        }
    }
    __syncthreads();

    if (tid < BM) {
        int row = tid;
        float ss = red_ss[row * 4 + 0] + red_ss[row * 4 + 1] + red_ss[row * 4 + 2] + red_ss[row * 4 + 3];
        float p0 = red_p0[row * 4 + 0] + red_p0[row * 4 + 1] + red_p0[row * 4 + 2] + red_p0[row * 4 + 3];
        float p1 = red_p1[row * 4 + 0] + red_p1[row * 4 + 1] + red_p1[row * 4 + 2] + red_p1[row * 4 + 3];
        float rn = 1.0f / fmaxf(sqrtf(ss), 1e-12f);
        float x0 = p0 * rn + f2b[0];
        float x1 = p1 * rn + f2b[1];
        float mu = 1.0f / (1.0f + expf(-x0));
        float th = (x1 > 0.f) ? (x1 + log1pf(expf(-x1))) : log1pf(expf(x1));
        long gr = m0 + row;
        out[(long)Bsz * NOUT + gr] = mu;
        out[(long)Bsz * NOUT + Bsz + gr] = th;
        red_rn[row] = rn;
    }
    __syncthreads();

#pragma unroll
    for (int mi = 0; mi < 4; ++mi) {
        float rn[4];
#pragma unroll
        for (int r = 0; r < 4; ++r) rn[r] = red_rn[mi * 16 + lhi * 4 + r];
#pragma unroll
        for (int ni = 0; ni < 4; ++ni) {
#pragma unroll
            for (int r = 0; r < 4; ++r) {
                long row = m0 + mi * 16 + lhi * 4 + r;
                out[row * NOUT + w * 64 + ni * 16 + l15] = acc[mi][ni][r] * rn[r];
            }
        }
    }
}

extern "C" void kernel_launch(void* const* d_in, const int* in_sizes, int n_in,
                              void* d_out, int out_size, void* d_ws, size_t ws_size,
                              hipStream_t stream) {
    const float* x   = (const float*)d_in[0];
    const int*   ei  = (const int*)d_in[1];
    const float* cw  = (const float*)d_in[2];
    const float* cb  = (const float*)d_in[3];
    const float* f1w = (const float*)d_in[4];
    const float* f1b = (const float*)d_in[5];
    const float* f2w = (const float*)d_in[6];
    const float* f2b = (const float*)d_in[7];
    float* out = (float*)d_out;

    const int Nn  = in_sizes[0] / 2;       // nodes
    const int Bsz = Nn / NPG;              // graphs
    const int E   = in_sizes[1] / 2;       // edges
    const int* dst = ei + E;

    float*  acc2g = (float*)d_ws;                      // [N][2] f32
    ushort* Wt    = (ushort*)(acc2g + (size_t)Nn * 2); // [256][896] bf16

    const int nAgg = Bsz / 8;                          // 8192 (8 graphs per block)
    const int nTr  = (KDIM / 32) * (NOUT / 32);        // 224

    k_agg<<<nAgg + nTr, 256, 0, stream>>>(x, dst, f1w, acc2g, Wt, nAgg);
    k_gemm<<<Bsz / BM, 256, 0, stream>>>(acc2g, Wt, cw, cb, f1b, f2w, f2b, out, Bsz);
}

// Round 3
// 84.231 us; speedup vs baseline: 3.9514x; 2.0669x over previous
//
#include <hip/hip_runtime.h>
#include <hip/hip_bf16.h>
#include <stdint.h>

#define NPG 28
#define KDIM 896
#define NOUT 256
#define BM 64
#define BK 32
#define KT (KDIM / BK)   // 28

typedef __attribute__((ext_vector_type(8))) __bf16 bf16x8;
typedef __attribute__((ext_vector_type(8))) ushort us8;
typedef __attribute__((ext_vector_type(4))) float f32x4;

__device__ __forceinline__ ushort f2bf(float v) {
    uint u = __float_as_uint(v);
    return (ushort)((u + 0x7fffu + ((u >> 16) & 1u)) >> 16);
}

__device__ __forceinline__ void gload_lds16(const void* g, void* l) {
    __builtin_amdgcn_global_load_lds(
        (const __attribute__((address_space(1))) void*)(uintptr_t)g,
        (__attribute__((address_space(3))) void*)(uintptr_t)l,
        16, 0, 0);
}

// ---------------- k_agg: atomic-free gather (unchanged) ----------------
__global__ __launch_bounds__(256) void k_agg(
    const float* __restrict__ x, const int* __restrict__ dst,
    const float* __restrict__ f1w,
    float* __restrict__ acc2g, ushort* __restrict__ wt, int nAgg)
{
    __shared__ int   pk[8][32];
    __shared__ float sx[8][32][2];
    __shared__ float t[32][33];

    const int tid = threadIdx.x;

    if ((int)blockIdx.x >= nAgg) {    // fc1_w transpose tiles
        int b = blockIdx.x - nAgg;
        int n0 = (b & 7) * 32, k0 = (b >> 3) * 32;
        int tx = tid & 31, ty = tid >> 5;
#pragma unroll
        for (int q = 0; q < 4; ++q)
            t[ty + q * 8][tx] = f1w[(k0 + ty + q * 8) * NOUT + n0 + tx];
        __syncthreads();
#pragma unroll
        for (int q = 0; q < 4; ++q)
            wt[(long)(n0 + ty + q * 8) * KDIM + k0 + tx] = f2bf(t[tx][ty + q * 8]);
        return;
    }

    const int g = tid >> 5;
    const int j = tid & 31;
    const long gb = ((long)blockIdx.x * 8 + g) * NPG;

    float2 xx = make_float2(0.f, 0.f);
    if (j < NPG) {
        int4 d4 = ((const int4*)dst)[gb + j];
        xx = ((const float2*)x)[gb + j];
        int gbi = (int)gb;
        pk[g][j] = (d4.x - gbi) | ((d4.y - gbi) << 8) |
                   ((d4.z - gbi) << 16) | ((d4.w - gbi) << 24);
    }
    __syncthreads();

    const uint repj = (uint)j * 0x01010101u;
    uint cp0 = 0, cp1 = 0, cp2 = 0, cp3 = 0;
    int cnt = 0;
#pragma unroll
    for (int s4 = 0; s4 < 7; ++s4) {
        int4 pv = *(const int4*)&pk[g][s4 * 4];
#pragma unroll
        for (int r = 0; r < 4; ++r) {
            uint v = ((const uint*)&pv)[r] ^ repj;
            uint zb = ~(((v & 0x7F7F7F7Fu) + 0x7F7F7F7Fu) | v) & 0x80808080u;
            uint c = (uint)__popc(zb);
            cnt += (int)c;
            int s = s4 * 4 + r;
            uint nib = c << ((s & 7) * 4);
            if (s < 8)       cp0 |= nib;
            else if (s < 16) cp1 |= nib;
            else if (s < 24) cp2 |= nib;
            else             cp3 |= nib;
        }
    }

    const float dinv = rsqrtf((float)(1 + cnt));
    const float sx0 = xx.x * dinv, sx1 = xx.y * dinv;
    if (j < NPG) {
        sx[g][j][0] = sx0;
        sx[g][j][1] = sx1;
    }
    __syncthreads();

    float a0 = sx0, a1 = sx1;
#pragma unroll
    for (int s = 0; s < NPG; ++s) {
        float2 sv = *(const float2*)&sx[g][s][0];
        uint cpw = (s < 8) ? cp0 : (s < 16) ? cp1 : (s < 24) ? cp2 : cp3;
        float cf = (float)((cpw >> ((s & 7) * 4)) & 0xFu);
        a0 += cf * sv.x;
        a1 += cf * sv.y;
    }

    if (j < NPG)
        ((float2*)acc2g)[gb + j] = make_float2(a0 * dinv, a1 * dinv);
}

// ---------------- k_gemm helpers (BM=64, BN=256, BK=32 geometry) ----------------
// Bs stage: 16KB per buffer, 4 gload_lds per wave-lane set (wave w covers rows w*64..w*64+63).
// LDS dest linear; global source granule pre-swizzled: phys = logical ^ ((row>>1)&3).
__device__ __forceinline__ void stage_b4(const char* WtB, ushort* BsX, int kt, int w, int l) {
    const int o = (l & 3) ^ ((l >> 3) & 3);
#pragma unroll
    for (int i = 0; i < 4; ++i) {
        int row = w * 64 + i * 16 + (l >> 2);
        gload_lds16(WtB + (long)row * (KDIM * 2) + kt * 64 + o * 16,
                    (char*)BsX + w * 4096 + i * 1024);
    }
}

// one K-step MFMA cluster: 4x4 16x16x32 tiles per wave (wave covers 64 rows x 64 cols)
__device__ __forceinline__ void mfma_phase(const ushort* AsX, const ushort* BsX,
                                           f32x4 acc[4][4], int a_off, int b_off) {
    bf16x8 bfr[4];
#pragma unroll
    for (int ni = 0; ni < 4; ++ni)
        bfr[ni] = *(const bf16x8*)(&BsX[b_off + ni * 512]);
#pragma unroll
    for (int mi = 0; mi < 4; ++mi) {
        bf16x8 af = *(const bf16x8*)(&AsX[a_off + mi * 512]);
#pragma unroll
        for (int ni = 0; ni < 4; ++ni)
            acc[mi][ni] = __builtin_amdgcn_mfma_f32_16x16x32_bf16(
                af, bfr[ni], acc[mi][ni], 0, 0, 0);
    }
}

// A-gen write-side: one feature-octet of one row (relu(conv)+bf16 pack).
// Octet is wave-uniform -> w0/w1/bb come from scalar loads (SGPRs).
__device__ __forceinline__ void agen_w(ushort* AsX, float2 av, int awoff,
                                       const float* w0, const float* w1, const float* bb) {
    union { us8 v; uint u[4]; } pk;
#pragma unroll
    for (int k = 0; k < 4; ++k) {
        float e0 = fmaxf(av.x * w0[2 * k]     + av.y * w1[2 * k]     + bb[2 * k],     0.f);
        float e1 = fmaxf(av.x * w0[2 * k + 1] + av.y * w1[2 * k + 1] + bb[2 * k + 1], 0.f);
        __hip_bfloat162 h = __float22bfloat162_rn(make_float2(e0, e1));
        pk.u[k] = *reinterpret_cast<uint*>(&h);
    }
    *(us8*)&AsX[awoff] = pk.v;
}

// ---------------- k_gemm: BM=64, BK=32, 4 waves (1Mx4N), dbuf, 3 blocks/CU ----------------
// launch_bounds(256,3): unified reg cap = 512/3 ~= 170 = 64 AGPR (acc) + ~106 arch.
// (256,4) capped at 128 = 64+64 and spilled ~830B/thread (round-2 FETCH 233MB).
__global__ __launch_bounds__(256, 3) void k_gemm(
    const float* __restrict__ acc2g, const ushort* __restrict__ Wt,
    const float* __restrict__ cw, const float* __restrict__ cb,
    const float* __restrict__ f1b, const float* __restrict__ f2w,
    const float* __restrict__ f2b, float* __restrict__ out, int Bsz)
{
    __shared__ ushort As0[BM * BK], As1[BM * BK];     // 2 x 4KB
    __shared__ ushort Bs0[NOUT * BK], Bs1[NOUT * BK]; // 2 x 16KB -> 40KB total

    const int tid = threadIdx.x;
    const int w = tid >> 6, l = tid & 63;
    const int l15 = l & 15, lhi = l >> 4;
    const long m0 = (long)blockIdx.x * BM;

    // A-gen: wave w computes feature-octet w for row l (octet wave-uniform -> SGPR weights)
    const int ao = __builtin_amdgcn_readfirstlane(w);
    const int ar = l;                                    // row 0..63
    const int awoff = ar * 32 + ((ao ^ ((ar >> 1) & 3)) * 8);
    float w0[8], w1[8], bb[8];
#pragma unroll
    for (int k = 0; k < 8; ++k) {
        w0[k] = cw[ao * 8 + k]; w1[k] = cw[32 + ao * 8 + k]; bb[k] = cb[ao * 8 + k];
    }

    // swizzled LDS read offsets ((row>>1)&3 == (l15>>1)&3 for 16-aligned row bases)
    const int swz = (lhi ^ ((l15 >> 1) & 3)) * 8;
    const int a_off = l15 * 32 + swz;                  // + mi*512
    const int b_off = (w * 64 + l15) * 32 + swz;       // + ni*512

    const float2* a2 = (const float2*)acc2g;
    const char* WtB = (const char*)Wt;
    const long arow = (m0 + ar) * NPG;

    f32x4 acc[4][4];
#pragma unroll
    for (int mi = 0; mi < 4; ++mi)
#pragma unroll
        for (int ni = 0; ni < 4; ++ni) acc[mi][ni] = (f32x4){0.f, 0.f, 0.f, 0.f};

    // prologue: fill buffers for kt=0
    {
        float2 av0 = a2[arow + 0];
        stage_b4(WtB, Bs0, 0, w, l);
        agen_w(As0, av0, awoff, w0, w1, bb);
    }
    __syncthreads();

    for (int kt = 0; kt < KT; kt += 2) {
        // process buf0 (kt); prefetch kt+1 -> buf1 (issue loads BEFORE mfma, write after)
        float2 av1 = a2[arow + kt + 1];
        stage_b4(WtB, Bs1, kt + 1, w, l);
        __builtin_amdgcn_s_setprio(1);
        mfma_phase(As0, Bs0, acc, a_off, b_off);
        __builtin_amdgcn_s_setprio(0);
        agen_w(As1, av1, awoff, w0, w1, bb);
        __syncthreads();

        // process buf1 (kt+1); prefetch kt+2 -> buf0
        if (kt + 2 < KT) {
            float2 av2 = a2[arow + kt + 2];
            stage_b4(WtB, Bs0, kt + 2, w, l);
            __builtin_amdgcn_s_setprio(1);
            mfma_phase(As1, Bs1, acc, a_off, b_off);
            __builtin_amdgcn_s_setprio(0);
            agen_w(As0, av2, awoff, w0, w1, bb);
            __syncthreads();
        } else {
            __builtin_amdgcn_s_setprio(1);
            mfma_phase(As1, Bs1, acc, a_off, b_off);
            __builtin_amdgcn_s_setprio(0);
        }
    }

    // ---- fused epilogue: +bias, row L2-norm, FC2, sigmoid/softplus ----
    float b1[4], w20[4], w21[4];
#pragma unroll
    for (int ni = 0; ni < 4; ++ni) {
        int col = w * 64 + ni * 16 + l15;
        b1[ni] = f1b[col];
        w20[ni] = f2w[col * 2 + 0];
        w21[ni] = f2w[col * 2 + 1];
    }
    float* red    = (float*)As0;     // As0 dead after last mid-loop barrier
    float* red_ss = red;             // [64][4]
    float* red_p0 = red + 256;
    float* red_p1 = red + 512;
    float* red_rn = red + 768;       // [64]

#pragma unroll
    for (int mi = 0; mi < 4; ++mi) {
        float ssr[4], p0r[4], p1r[4];
#pragma unroll
        for (int r = 0; r < 4; ++r) { ssr[r] = 0.f; p0r[r] = 0.f; p1r[r] = 0.f; }
#pragma unroll
        for (int ni = 0; ni < 4; ++ni) {
#pragma unroll
            for (int r = 0; r < 4; ++r) {
                float v = acc[mi][ni][r] + b1[ni];
                acc[mi][ni][r] = v;
                ssr[r] += v * v;
                p0r[r] += v * w20[ni];
                p1r[r] += v * w21[ni];
            }
        }
#pragma unroll
        for (int m = 1; m < 16; m <<= 1) {
#pragma unroll
            for (int r = 0; r < 4; ++r) {
                ssr[r] += __shfl_xor(ssr[r], m);
                p0r[r] += __shfl_xor(p0r[r], m);
                p1r[r] += __shfl_xor(p1r[r], m);
            }
        }
        if (l15 == 0) {
            int rowb = mi * 16 + lhi * 4;
#pragma unroll
            for (int r = 0; r < 4; ++r) {
                red_ss[(rowb + r) * 4 + w] = ssr[r];
                red_p0[(rowb + r) * 4 + w] = p0r[r];
                red_p1[(rowb + r) * 4 + w] = p1r[r];
            }
        }
    }
    __syncthreads();

    if (tid < BM) {
        int row = tid;
        float ss = red_ss[row * 4 + 0] + red_ss[row * 4 + 1] + red_ss[row * 4 + 2] + red_ss[row * 4 + 3];
        float p0 = red_p0[row * 4 + 0] + red_p0[row * 4 + 1] + red_p0[row * 4 + 2] + red_p0[row * 4 + 3];
        float p1 = red_p1[row * 4 + 0] + red_p1[row * 4 + 1] + red_p1[row * 4 + 2] + red_p1[row * 4 + 3];
        float rn = 1.0f / fmaxf(sqrtf(ss), 1e-12f);
        float x0 = p0 * rn + f2b[0];
        float x1 = p1 * rn + f2b[1];
        float mu = 1.0f / (1.0f + expf(-x0));
        float th = (x1 > 0.f) ? (x1 + log1pf(expf(-x1))) : log1pf(expf(x1));
        long gr = m0 + row;
        out[(long)Bsz * NOUT + gr] = mu;
        out[(long)Bsz * NOUT + Bsz + gr] = th;
        red_rn[row] = rn;
    }
    __syncthreads();

#pragma unroll
    for (int mi = 0; mi < 4; ++mi) {
        float rn[4];
#pragma unroll
        for (int r = 0; r < 4; ++r) rn[r] = red_rn[mi * 16 + lhi * 4 + r];
#pragma unroll
        for (int ni = 0; ni < 4; ++ni) {
#pragma unroll
            for (int r = 0; r < 4; ++r) {
                long row = m0 + mi * 16 + lhi * 4 + r;
                out[row * NOUT + w * 64 + ni * 16 + l15] = acc[mi][ni][r] * rn[r];
            }
        }
    }
}

extern "C" void kernel_launch(void* const* d_in, const int* in_sizes, int n_in,
                              void* d_out, int out_size, void* d_ws, size_t ws_size,
                              hipStream_t stream) {
    const float* x   = (const float*)d_in[0];
    const int*   ei  = (const int*)d_in[1];
    const float* cw  = (const float*)d_in[2];
    const float* cb  = (const float*)d_in[3];
    const float* f1w = (const float*)d_in[4];
    const float* f1b = (const float*)d_in[5];
    const float* f2w = (const float*)d_in[6];
    const float* f2b = (const float*)d_in[7];
    float* out = (float*)d_out;

    const int Nn  = in_sizes[0] / 2;       // nodes
    const int Bsz = Nn / NPG;              // graphs
    const int E   = in_sizes[1] / 2;       // edges
    const int* dst = ei + E;

    float*  acc2g = (float*)d_ws;                      // [N][2] f32
    ushort* Wt    = (ushort*)(acc2g + (size_t)Nn * 2); // [256][896] bf16

    const int nAgg = Bsz / 8;                          // 8192 (8 graphs per block)
    const int nTr  = (KDIM / 32) * (NOUT / 32);        // 224

    k_agg<<<nAgg + nTr, 256, 0, stream>>>(x, dst, f1w, acc2g, Wt, nAgg);
    k_gemm<<<Bsz / BM, 256, 0, stream>>>(acc2g, Wt, cw, cb, f1b, f2w, f2b, out, Bsz);
}

// Round 4
// 83.720 us; speedup vs baseline: 3.9756x; 1.0061x over previous
//
#include <hip/hip_runtime.h>
#include <hip/hip_bf16.h>
#include <stdint.h>

#define NPG 28
#define KDIM 896
#define NOUT 256
#define BM 64
#define BK 32
#define KT (KDIM / BK)   // 28

typedef __attribute__((ext_vector_type(8))) __bf16 bf16x8;
typedef __attribute__((ext_vector_type(8))) ushort us8;
typedef __attribute__((ext_vector_type(4))) float f32x4;

__device__ __forceinline__ ushort f2bf(float v) {
    uint u = __float_as_uint(v);
    return (ushort)((u + 0x7fffu + ((u >> 16) & 1u)) >> 16);
}

__device__ __forceinline__ void gload_lds16(const void* g, void* l) {
    __builtin_amdgcn_global_load_lds(
        (const __attribute__((address_space(1))) void*)(uintptr_t)g,
        (__attribute__((address_space(3))) void*)(uintptr_t)l,
        16, 0, 0);
}

// ---------------- k_agg: atomic-free gather (unchanged) ----------------
__global__ __launch_bounds__(256) void k_agg(
    const float* __restrict__ x, const int* __restrict__ dst,
    const float* __restrict__ f1w,
    float* __restrict__ acc2g, ushort* __restrict__ wt, int nAgg)
{
    __shared__ int   pk[8][32];
    __shared__ float sx[8][32][2];
    __shared__ float t[32][33];

    const int tid = threadIdx.x;

    if ((int)blockIdx.x >= nAgg) {    // fc1_w transpose tiles
        int b = blockIdx.x - nAgg;
        int n0 = (b & 7) * 32, k0 = (b >> 3) * 32;
        int tx = tid & 31, ty = tid >> 5;
#pragma unroll
        for (int q = 0; q < 4; ++q)
            t[ty + q * 8][tx] = f1w[(k0 + ty + q * 8) * NOUT + n0 + tx];
        __syncthreads();
#pragma unroll
        for (int q = 0; q < 4; ++q)
            wt[(long)(n0 + ty + q * 8) * KDIM + k0 + tx] = f2bf(t[tx][ty + q * 8]);
        return;
    }

    const int g = tid >> 5;
    const int j = tid & 31;
    const long gb = ((long)blockIdx.x * 8 + g) * NPG;

    float2 xx = make_float2(0.f, 0.f);
    if (j < NPG) {
        int4 d4 = ((const int4*)dst)[gb + j];
        xx = ((const float2*)x)[gb + j];
        int gbi = (int)gb;
        pk[g][j] = (d4.x - gbi) | ((d4.y - gbi) << 8) |
                   ((d4.z - gbi) << 16) | ((d4.w - gbi) << 24);
    }
    __syncthreads();

    const uint repj = (uint)j * 0x01010101u;
    uint cp0 = 0, cp1 = 0, cp2 = 0, cp3 = 0;
    int cnt = 0;
#pragma unroll
    for (int s4 = 0; s4 < 7; ++s4) {
        int4 pv = *(const int4*)&pk[g][s4 * 4];
#pragma unroll
        for (int r = 0; r < 4; ++r) {
            uint v = ((const uint*)&pv)[r] ^ repj;
            uint zb = ~(((v & 0x7F7F7F7Fu) + 0x7F7F7F7Fu) | v) & 0x80808080u;
            uint c = (uint)__popc(zb);
            cnt += (int)c;
            int s = s4 * 4 + r;
            uint nib = c << ((s & 7) * 4);
            if (s < 8)       cp0 |= nib;
            else if (s < 16) cp1 |= nib;
            else if (s < 24) cp2 |= nib;
            else             cp3 |= nib;
        }
    }

    const float dinv = rsqrtf((float)(1 + cnt));
    const float sx0 = xx.x * dinv, sx1 = xx.y * dinv;
    if (j < NPG) {
        sx[g][j][0] = sx0;
        sx[g][j][1] = sx1;
    }
    __syncthreads();

    float a0 = sx0, a1 = sx1;
#pragma unroll
    for (int s = 0; s < NPG; ++s) {
        float2 sv = *(const float2*)&sx[g][s][0];
        uint cpw = (s < 8) ? cp0 : (s < 16) ? cp1 : (s < 24) ? cp2 : cp3;
        float cf = (float)((cpw >> ((s & 7) * 4)) & 0xFu);
        a0 += cf * sv.x;
        a1 += cf * sv.y;
    }

    if (j < NPG)
        ((float2*)acc2g)[gb + j] = make_float2(a0 * dinv, a1 * dinv);
}

// ---------------- k_gemm helpers ----------------
// Bs stage: wave w stages EXACTLY the rows it alone reads (w*64..w*64+63) -> no barrier needed.
// LDS dest linear; global source granule pre-swizzled: phys = logical ^ ((row>>1)&3).
__device__ __forceinline__ void stage_b4(const char* WtB, ushort* BsX, int kt, int w, int l) {
    const int o = (l & 3) ^ ((l >> 3) & 3);
#pragma unroll
    for (int i = 0; i < 4; ++i) {
        int row = w * 64 + i * 16 + (l >> 2);
        gload_lds16(WtB + (long)row * (KDIM * 2) + kt * 64 + o * 16,
                    (char*)BsX + w * 4096 + i * 1024);
    }
}

// one K-step: ds_read B-frags, generate A-frags in-register from LDS-resident A panel, MFMA.
__device__ __forceinline__ void compute_phase(const ushort* BsX, const float2* Af,
                                              int kt, int b_off, int l15,
                                              const float* w0, const float* w1, const float* bb,
                                              f32x4 acc[4][4]) {
    bf16x8 bfr[4];
#pragma unroll
    for (int ni = 0; ni < 4; ++ni)
        bfr[ni] = *(const bf16x8*)(&BsX[b_off + ni * 512]);
    __builtin_amdgcn_s_setprio(1);
#pragma unroll
    for (int mi = 0; mi < 4; ++mi) {
        float2 av = Af[(mi * 16 + l15) * 29 + kt];
        union { us8 v; uint u[4]; } pk;
#pragma unroll
        for (int k = 0; k < 4; ++k) {
            float e0 = fmaxf(av.x * w0[2 * k]     + av.y * w1[2 * k]     + bb[2 * k],     0.f);
            float e1 = fmaxf(av.x * w0[2 * k + 1] + av.y * w1[2 * k + 1] + bb[2 * k + 1], 0.f);
            __hip_bfloat162 h = __float22bfloat162_rn(make_float2(e0, e1));
            pk.u[k] = *reinterpret_cast<uint*>(&h);
        }
        bf16x8 af = *reinterpret_cast<bf16x8*>(&pk.v);
#pragma unroll
        for (int ni = 0; ni < 4; ++ni)
            acc[mi][ni] = __builtin_amdgcn_mfma_f32_16x16x32_bf16(
                af, bfr[ni], acc[mi][ni], 0, 0, 0);
    }
    __builtin_amdgcn_s_setprio(0);
}

// ---------------- k_gemm: BM=64, barrier-free main loop, per-wave counted vmcnt ----------------
__global__ __launch_bounds__(256, 3) void k_gemm(
    const float* __restrict__ acc2g, const ushort* __restrict__ Wt,
    const float* __restrict__ cw, const float* __restrict__ cb,
    const float* __restrict__ f1b, const float* __restrict__ f2w,
    const float* __restrict__ f2b, float* __restrict__ out, int Bsz)
{
    __shared__ float2 Af[64 * 29];                    // A panel, f32, 29-pad (14.5KB)
    __shared__ ushort Bs0[NOUT * BK], Bs1[NOUT * BK]; // 2 x 16KB -> total ~46.5KB, 3 blocks/CU

    const int tid = threadIdx.x;
    const int w = tid >> 6, l = tid & 63;
    const int l15 = l & 15, lhi = (l >> 4) & 3;
    const long m0 = (long)blockIdx.x * BM;

    // ---- A panel -> LDS, coalesced, once ----
    {
        const float2* a2 = (const float2*)acc2g + (size_t)m0 * NPG;
#pragma unroll
        for (int i = 0; i < 7; ++i) {
            int idx = tid + i * 256;          // 0..1791 = 64*28
            int r = idx / 28;
            int c = idx - r * 28;
            Af[r * 29 + c] = a2[idx];
        }
    }

    // conv weights for this lane's k-octet (lhi) -> VGPRs
    float w0[8], w1[8], bb[8];
#pragma unroll
    for (int k = 0; k < 8; ++k) {
        w0[k] = cw[lhi * 8 + k]; w1[k] = cw[32 + lhi * 8 + k]; bb[k] = cb[lhi * 8 + k];
    }

    const int b_off = (w * 64 + l15) * 32 + ((lhi ^ ((l15 >> 1) & 3)) * 8);
    const char* WtB = (const char*)Wt;

    f32x4 acc[4][4];
#pragma unroll
    for (int mi = 0; mi < 4; ++mi)
#pragma unroll
        for (int ni = 0; ni < 4; ++ni) acc[mi][ni] = (f32x4){0.f, 0.f, 0.f, 0.f};

    // prologue: stage kt=0; barrier publishes Af (drains prologue stage too)
    stage_b4(WtB, Bs0, 0, w, l);
    __syncthreads();

    // barrier-free main loop: prefetch depth 1, counted vmcnt(4) leaves prefetch in flight
    for (int kt = 0; kt < KT; kt += 2) {
        stage_b4(WtB, Bs1, kt + 1, w, l);
        asm volatile("s_waitcnt vmcnt(4)" ::: "memory");
        compute_phase(Bs0, Af, kt, b_off, l15, w0, w1, bb, acc);

        if (kt + 2 < KT) {
            stage_b4(WtB, Bs0, kt + 2, w, l);
            asm volatile("s_waitcnt vmcnt(4)" ::: "memory");
        } else {
            asm volatile("s_waitcnt vmcnt(0)" ::: "memory");
        }
        compute_phase(Bs1, Af, kt + 1, b_off, l15, w0, w1, bb, acc);
    }

    __syncthreads();   // protect Af before reuse as reduction scratch (waves are decoupled)

    // ---- fused epilogue: +bias, row L2-norm, FC2, sigmoid/softplus ----
    float b1[4], w20[4], w21[4];
#pragma unroll
    for (int ni = 0; ni < 4; ++ni) {
        int col = w * 64 + ni * 16 + l15;
        b1[ni] = f1b[col];
        w20[ni] = f2w[col * 2 + 0];
        w21[ni] = f2w[col * 2 + 1];
    }
    float* red    = (float*)Af;
    float* red_ss = red;             // [64][4]
    float* red_p0 = red + 256;
    float* red_p1 = red + 512;
    float* red_rn = red + 768;       // [64]

#pragma unroll
    for (int mi = 0; mi < 4; ++mi) {
        float ssr[4], p0r[4], p1r[4];
#pragma unroll
        for (int r = 0; r < 4; ++r) { ssr[r] = 0.f; p0r[r] = 0.f; p1r[r] = 0.f; }
#pragma unroll
        for (int ni = 0; ni < 4; ++ni) {
#pragma unroll
            for (int r = 0; r < 4; ++r) {
                float v = acc[mi][ni][r] + b1[ni];
                acc[mi][ni][r] = v;
                ssr[r] += v * v;
                p0r[r] += v * w20[ni];
                p1r[r] += v * w21[ni];
            }
        }
#pragma unroll
        for (int m = 1; m < 16; m <<= 1) {
#pragma unroll
            for (int r = 0; r < 4; ++r) {
                ssr[r] += __shfl_xor(ssr[r], m);
                p0r[r] += __shfl_xor(p0r[r], m);
                p1r[r] += __shfl_xor(p1r[r], m);
            }
        }
        if (l15 == 0) {
            int rowb = mi * 16 + lhi * 4;
#pragma unroll
            for (int r = 0; r < 4; ++r) {
                red_ss[(rowb + r) * 4 + w] = ssr[r];
                red_p0[(rowb + r) * 4 + w] = p0r[r];
                red_p1[(rowb + r) * 4 + w] = p1r[r];
            }
        }
    }
    __syncthreads();

    if (tid < BM) {
        int row = tid;
        float ss = red_ss[row * 4 + 0] + red_ss[row * 4 + 1] + red_ss[row * 4 + 2] + red_ss[row * 4 + 3];
        float p0 = red_p0[row * 4 + 0] + red_p0[row * 4 + 1] + red_p0[row * 4 + 2] + red_p0[row * 4 + 3];
        float p1 = red_p1[row * 4 + 0] + red_p1[row * 4 + 1] + red_p1[row * 4 + 2] + red_p1[row * 4 + 3];
        float rn = 1.0f / fmaxf(sqrtf(ss), 1e-12f);
        float x0 = p0 * rn + f2b[0];
        float x1 = p1 * rn + f2b[1];
        float mu = 1.0f / (1.0f + expf(-x0));
        float th = (x1 > 0.f) ? (x1 + log1pf(expf(-x1))) : log1pf(expf(x1));
        long gr = m0 + row;
        out[(long)Bsz * NOUT + gr] = mu;
        out[(long)Bsz * NOUT + Bsz + gr] = th;
        red_rn[row] = rn;
    }
    __syncthreads();

#pragma unroll
    for (int mi = 0; mi < 4; ++mi) {
        float rn[4];
#pragma unroll
        for (int r = 0; r < 4; ++r) rn[r] = red_rn[mi * 16 + lhi * 4 + r];
#pragma unroll
        for (int ni = 0; ni < 4; ++ni) {
#pragma unroll
            for (int r = 0; r < 4; ++r) {
                long row = m0 + mi * 16 + lhi * 4 + r;
                out[row * NOUT + w * 64 + ni * 16 + l15] = acc[mi][ni][r] * rn[r];
            }
        }
    }
}

extern "C" void kernel_launch(void* const* d_in, const int* in_sizes, int n_in,
                              void* d_out, int out_size, void* d_ws, size_t ws_size,
                              hipStream_t stream) {
    const float* x   = (const float*)d_in[0];
    const int*   ei  = (const int*)d_in[1];
    const float* cw  = (const float*)d_in[2];
    const float* cb  = (const float*)d_in[3];
    const float* f1w = (const float*)d_in[4];
    const float* f1b = (const float*)d_in[5];
    const float* f2w = (const float*)d_in[6];
    const float* f2b = (const float*)d_in[7];
    float* out = (float*)d_out;

    const int Nn  = in_sizes[0] / 2;       // nodes
    const int Bsz = Nn / NPG;              // graphs
    const int E   = in_sizes[1] / 2;       // edges
    const int* dst = ei + E;

    float*  acc2g = (float*)d_ws;                      // [N][2] f32
    ushort* Wt    = (ushort*)(acc2g + (size_t)Nn * 2); // [256][896] bf16

    const int nAgg = Bsz / 8;                          // 8192 (8 graphs per block)
    const int nTr  = (KDIM / 32) * (NOUT / 32);        // 224

    k_agg<<<nAgg + nTr, 256, 0, stream>>>(x, dst, f1w, acc2g, Wt, nAgg);
    k_gemm<<<Bsz / BM, 256, 0, stream>>>(acc2g, Wt, cw, cb, f1b, f2w, f2b, out, Bsz);
}

// Round 6
// 79.671 us; speedup vs baseline: 4.1776x; 1.0508x over previous
//
#include <hip/hip_runtime.h>
#include <hip/hip_bf16.h>
#include <stdint.h>

#define NPG 28
#define KDIM 896
#define NOUT 256
#define BM 64
#define BK 32
#define KT (KDIM / BK)   // 28

typedef __attribute__((ext_vector_type(8))) __bf16 bf16x8;
typedef __attribute__((ext_vector_type(8))) ushort us8;
typedef __attribute__((ext_vector_type(4))) float f32x4;

__device__ __forceinline__ ushort f2bf(float v) {
    uint u = __float_as_uint(v);
    return (ushort)((u + 0x7fffu + ((u >> 16) & 1u)) >> 16);
}

__device__ __forceinline__ void gload_lds16(const void* g, void* l) {
    __builtin_amdgcn_global_load_lds(
        (const __attribute__((address_space(1))) void*)(uintptr_t)g,
        (__attribute__((address_space(3))) void*)(uintptr_t)l,
        16, 0, 0);
}

// ---------------- k_agg: atomic-free gather (unchanged) ----------------
__global__ __launch_bounds__(256) void k_agg(
    const float* __restrict__ x, const int* __restrict__ dst,
    const float* __restrict__ f1w,
    float* __restrict__ acc2g, ushort* __restrict__ wt, int nAgg)
{
    __shared__ int   pk[8][32];
    __shared__ float sx[8][32][2];
    __shared__ float t[32][33];

    const int tid = threadIdx.x;

    if ((int)blockIdx.x >= nAgg) {    // fc1_w transpose tiles
        int b = blockIdx.x - nAgg;
        int n0 = (b & 7) * 32, k0 = (b >> 3) * 32;
        int tx = tid & 31, ty = tid >> 5;
#pragma unroll
        for (int q = 0; q < 4; ++q)
            t[ty + q * 8][tx] = f1w[(k0 + ty + q * 8) * NOUT + n0 + tx];
        __syncthreads();
#pragma unroll
        for (int q = 0; q < 4; ++q)
            wt[(long)(n0 + ty + q * 8) * KDIM + k0 + tx] = f2bf(t[tx][ty + q * 8]);
        return;
    }

    const int g = tid >> 5;
    const int j = tid & 31;
    const long gb = ((long)blockIdx.x * 8 + g) * NPG;

    float2 xx = make_float2(0.f, 0.f);
    if (j < NPG) {
        int4 d4 = ((const int4*)dst)[gb + j];
        xx = ((const float2*)x)[gb + j];
        int gbi = (int)gb;
        pk[g][j] = (d4.x - gbi) | ((d4.y - gbi) << 8) |
                   ((d4.z - gbi) << 16) | ((d4.w - gbi) << 24);
    }
    __syncthreads();

    const uint repj = (uint)j * 0x01010101u;
    uint cp0 = 0, cp1 = 0, cp2 = 0, cp3 = 0;
    int cnt = 0;
#pragma unroll
    for (int s4 = 0; s4 < 7; ++s4) {
        int4 pv = *(const int4*)&pk[g][s4 * 4];
#pragma unroll
        for (int r = 0; r < 4; ++r) {
            uint v = ((const uint*)&pv)[r] ^ repj;
            uint zb = ~(((v & 0x7F7F7F7Fu) + 0x7F7F7F7Fu) | v) & 0x80808080u;
            uint c = (uint)__popc(zb);
            cnt += (int)c;
            int s = s4 * 4 + r;
            uint nib = c << ((s & 7) * 4);
            if (s < 8)       cp0 |= nib;
            else if (s < 16) cp1 |= nib;
            else if (s < 24) cp2 |= nib;
            else             cp3 |= nib;
        }
    }

    const float dinv = rsqrtf((float)(1 + cnt));
    const float sx0 = xx.x * dinv, sx1 = xx.y * dinv;
    if (j < NPG) {
        sx[g][j][0] = sx0;
        sx[g][j][1] = sx1;
    }
    __syncthreads();

    float a0 = sx0, a1 = sx1;
#pragma unroll
    for (int s = 0; s < NPG; ++s) {
        float2 sv = *(const float2*)&sx[g][s][0];
        uint cpw = (s < 8) ? cp0 : (s < 16) ? cp1 : (s < 24) ? cp2 : cp3;
        float cf = (float)((cpw >> ((s & 7) * 4)) & 0xFu);
        a0 += cf * sv.x;
        a1 += cf * sv.y;
    }

    if (j < NPG)
        ((float2*)acc2g)[gb + j] = make_float2(a0 * dinv, a1 * dinv);
}

// ---------------- k_gemm helpers ----------------
// Bs stage: wave w stages EXACTLY the rows it alone reads (w*64..w*64+63).
// LDS dest linear; global source granule pre-swizzled: phys = logical ^ ((row>>1)&3).
__device__ __forceinline__ void stage_b4(const char* WtB, ushort* BsX, int kt, int w, int l) {
    const int o = (l & 3) ^ ((l >> 3) & 3);
#pragma unroll
    for (int i = 0; i < 4; ++i) {
        int row = w * 64 + i * 16 + (l >> 2);
        gload_lds16(WtB + (long)row * (KDIM * 2) + kt * 64 + o * 16,
                    (char*)BsX + w * 4096 + i * 1024);
    }
}

// distributed A-gen: wave w generates feature-octet w of row l (one us8 -> ds_write_b128).
// Octet is wave-uniform -> conv weights live in SGPRs.
__device__ __forceinline__ void agen_write(ushort* AsX, float2 av, int awoff,
                                           const float* w0, const float* w1, const float* bb) {
    union { us8 v; uint u[4]; } pk;
#pragma unroll
    for (int k = 0; k < 4; ++k) {
        float e0 = fmaxf(av.x * w0[2 * k]     + av.y * w1[2 * k]     + bb[2 * k],     0.f);
        float e1 = fmaxf(av.x * w0[2 * k + 1] + av.y * w1[2 * k + 1] + bb[2 * k + 1], 0.f);
        __hip_bfloat162 h = __float22bfloat162_rn(make_float2(e0, e1));
        pk.u[k] = *reinterpret_cast<uint*>(&h);
    }
    *(us8*)&AsX[awoff] = pk.v;
}

// one K-step MFMA cluster: ds_read A/B fragments, 16 MFMAs (T5 around pure-MFMA region)
__device__ __forceinline__ void compute_mfma(const ushort* AsX, const ushort* BsX,
                                             f32x4 acc[4][4], int a_off, int b_off) {
    bf16x8 bfr[4], afr[4];
#pragma unroll
    for (int ni = 0; ni < 4; ++ni)
        bfr[ni] = *(const bf16x8*)(&BsX[b_off + ni * 512]);
#pragma unroll
    for (int mi = 0; mi < 4; ++mi)
        afr[mi] = *(const bf16x8*)(&AsX[a_off + mi * 512]);
    __builtin_amdgcn_s_setprio(1);
#pragma unroll
    for (int mi = 0; mi < 4; ++mi)
#pragma unroll
        for (int ni = 0; ni < 4; ++ni)
            acc[mi][ni] = __builtin_amdgcn_mfma_f32_16x16x32_bf16(
                afr[mi], bfr[ni], acc[mi][ni], 0, 0, 0);
    __builtin_amdgcn_s_setprio(0);
}

// ---------------- k_gemm: distributed A-gen, raw-barrier pipeline ----------------
// Barriers carry ONLY the LDS As hand-off (lgkmcnt(0) before s_barrier); each wave drains
// its own VMEM with vmcnt(0) AFTER the barrier (robust to issue-order: round-5's counted
// vmcnt(1) raced when the compiler hoisted the av prefetch above the gload_lds stage).
__global__ __launch_bounds__(256, 3) void k_gemm(
    const float* __restrict__ acc2g, const ushort* __restrict__ Wt,
    const float* __restrict__ cw, const float* __restrict__ cb,
    const float* __restrict__ f1b, const float* __restrict__ f2w,
    const float* __restrict__ f2b, float* __restrict__ out, int Bsz)
{
    __shared__ ushort As0[BM * BK], As1[BM * BK];     // 2 x 4KB
    __shared__ ushort Bs0[NOUT * BK], Bs1[NOUT * BK]; // 2 x 16KB -> 40KB total

    const int tid = threadIdx.x;
    const int w = tid >> 6, l = tid & 63;
    const int l15 = l & 15, lhi = (l >> 4) & 3;
    const long m0 = (long)blockIdx.x * BM;

    // A-gen role: wave w -> octet w (wave-uniform, SGPR weights), row l
    const int ao = __builtin_amdgcn_readfirstlane(w);
    const int awoff = l * 32 + ((ao ^ ((l >> 1) & 3)) * 8);
    float w0[8], w1[8], bb[8];
#pragma unroll
    for (int k = 0; k < 8; ++k) {
        w0[k] = cw[ao * 8 + k]; w1[k] = cw[32 + ao * 8 + k]; bb[k] = cb[ao * 8 + k];
    }

    const int swz = (lhi ^ ((l15 >> 1) & 3)) * 8;
    const int a_off = l15 * 32 + swz;                  // + mi*512
    const int b_off = (w * 64 + l15) * 32 + swz;       // + ni*512

    const float2* a2 = (const float2*)acc2g;
    const char* WtB = (const char*)Wt;
    const long arow = (m0 + l) * NPG;

    f32x4 acc[4][4];
#pragma unroll
    for (int mi = 0; mi < 4; ++mi)
#pragma unroll
        for (int ni = 0; ni < 4; ++ni) acc[mi][ni] = (f32x4){0.f, 0.f, 0.f, 0.f};

    // prologue: A(0)->As0, Bs(0) staged, av(1) in flight; full drain once
    {
        float2 av0 = a2[arow + 0];
        stage_b4(WtB, Bs0, 0, w, l);
        agen_write(As0, av0, awoff, w0, w1, bb);
    }
    float2 avn = a2[arow + 1];
    __syncthreads();

    // steady loop: phases 0..25 (13 double-phases), peel 26/27
    for (int kt = 0; kt < KT - 2; kt += 2) {
        // phase kt (cur = buf0): build kt+1 into buf1
        stage_b4(WtB, Bs1, kt + 1, w, l);
        float2 avn2 = a2[arow + kt + 2];
        agen_write(As1, avn, awoff, w0, w1, bb);          // compiler waits avn's vmcnt exactly
        compute_mfma(As0, Bs0, acc, a_off, b_off);
        asm volatile("s_waitcnt lgkmcnt(0)" ::: "memory"); // As1 writes + all ds_reads done
        __builtin_amdgcn_s_barrier();
        asm volatile("s_waitcnt vmcnt(0)" ::: "memory");   // own Bs1 stage (+av) drained, post-barrier

        // phase kt+1 (cur = buf1): build kt+2 into buf0
        stage_b4(WtB, Bs0, kt + 2, w, l);
        avn = a2[arow + kt + 3];
        agen_write(As0, avn2, awoff, w0, w1, bb);
        compute_mfma(As1, Bs1, acc, a_off, b_off);
        asm volatile("s_waitcnt lgkmcnt(0)" ::: "memory");
        __builtin_amdgcn_s_barrier();
        asm volatile("s_waitcnt vmcnt(0)" ::: "memory");
    }
    // phase 26 (cur = buf0): build 27 into buf1
    {
        stage_b4(WtB, Bs1, KT - 1, w, l);
        agen_write(As1, avn, awoff, w0, w1, bb);
        compute_mfma(As0, Bs0, acc, a_off, b_off);
        asm volatile("s_waitcnt lgkmcnt(0)" ::: "memory");
        __builtin_amdgcn_s_barrier();
        asm volatile("s_waitcnt vmcnt(0)" ::: "memory");
        // phase 27
        compute_mfma(As1, Bs1, acc, a_off, b_off);
    }
    __syncthreads();   // protect As0 before reuse as reduction scratch

    // ---- fused epilogue: +bias, row L2-norm, FC2, sigmoid/softplus ----
    float b1[4], w20[4], w21[4];
#pragma unroll
    for (int ni = 0; ni < 4; ++ni) {
        int col = w * 64 + ni * 16 + l15;
        b1[ni] = f1b[col];
        w20[ni] = f2w[col * 2 + 0];
        w21[ni] = f2w[col * 2 + 1];
    }
    float* red    = (float*)As0;
    float* red_ss = red;             // [64][4]
    float* red_p0 = red + 256;
    float* red_p1 = red + 512;
    float* red_rn = red + 768;       // [64]

#pragma unroll
    for (int mi = 0; mi < 4; ++mi) {
        float ssr[4], p0r[4], p1r[4];
#pragma unroll
        for (int r = 0; r < 4; ++r) { ssr[r] = 0.f; p0r[r] = 0.f; p1r[r] = 0.f; }
#pragma unroll
        for (int ni = 0; ni < 4; ++ni) {
#pragma unroll
            for (int r = 0; r < 4; ++r) {
                float v = acc[mi][ni][r] + b1[ni];
                acc[mi][ni][r] = v;
                ssr[r] += v * v;
                p0r[r] += v * w20[ni];
                p1r[r] += v * w21[ni];
            }
        }
#pragma unroll
        for (int m = 1; m < 16; m <<= 1) {
#pragma unroll
            for (int r = 0; r < 4; ++r) {
                ssr[r] += __shfl_xor(ssr[r], m);
                p0r[r] += __shfl_xor(p0r[r], m);
                p1r[r] += __shfl_xor(p1r[r], m);
            }
        }
        if (l15 == 0) {
            int rowb = mi * 16 + lhi * 4;
#pragma unroll
            for (int r = 0; r < 4; ++r) {
                red_ss[(rowb + r) * 4 + w] = ssr[r];
                red_p0[(rowb + r) * 4 + w] = p0r[r];
                red_p1[(rowb + r) * 4 + w] = p1r[r];
            }
        }
    }
    __syncthreads();

    if (tid < BM) {
        int row = tid;
        float ss = red_ss[row * 4 + 0] + red_ss[row * 4 + 1] + red_ss[row * 4 + 2] + red_ss[row * 4 + 3];
        float p0 = red_p0[row * 4 + 0] + red_p0[row * 4 + 1] + red_p0[row * 4 + 2] + red_p0[row * 4 + 3];
        float p1 = red_p1[row * 4 + 0] + red_p1[row * 4 + 1] + red_p1[row * 4 + 2] + red_p1[row * 4 + 3];
        float rn = 1.0f / fmaxf(sqrtf(ss), 1e-12f);
        float x0 = p0 * rn + f2b[0];
        float x1 = p1 * rn + f2b[1];
        float mu = 1.0f / (1.0f + expf(-x0));
        float th = (x1 > 0.f) ? (x1 + log1pf(expf(-x1))) : log1pf(expf(x1));
        long gr = m0 + row;
        out[(long)Bsz * NOUT + gr] = mu;
        out[(long)Bsz * NOUT + Bsz + gr] = th;
        red_rn[row] = rn;
    }
    __syncthreads();

#pragma unroll
    for (int mi = 0; mi < 4; ++mi) {
        float rn[4];
#pragma unroll
        for (int r = 0; r < 4; ++r) rn[r] = red_rn[mi * 16 + lhi * 4 + r];
#pragma unroll
        for (int ni = 0; ni < 4; ++ni) {
#pragma unroll
            for (int r = 0; r < 4; ++r) {
                long row = m0 + mi * 16 + lhi * 4 + r;
                out[row * NOUT + w * 64 + ni * 16 + l15] = acc[mi][ni][r] * rn[r];
            }
        }
    }
}

extern "C" void kernel_launch(void* const* d_in, const int* in_sizes, int n_in,
                              void* d_out, int out_size, void* d_ws, size_t ws_size,
                              hipStream_t stream) {
    const float* x   = (const float*)d_in[0];
    const int*   ei  = (const int*)d_in[1];
    const float* cw  = (const float*)d_in[2];
    const float* cb  = (const float*)d_in[3];
    const float* f1w = (const float*)d_in[4];
    const float* f1b = (const float*)d_in[5];
    const float* f2w = (const float*)d_in[6];
    const float* f2b = (const float*)d_in[7];
    float* out = (float*)d_out;

    const int Nn  = in_sizes[0] / 2;       // nodes
    const int Bsz = Nn / NPG;              // graphs
    const int E   = in_sizes[1] / 2;       // edges
    const int* dst = ei + E;

    float*  acc2g = (float*)d_ws;                      // [N][2] f32
    ushort* Wt    = (ushort*)(acc2g + (size_t)Nn * 2); // [256][896] bf16

    const int nAgg = Bsz / 8;                          // 8192 (8 graphs per block)
    const int nTr  = (KDIM / 32) * (NOUT / 32);        // 224

    k_agg<<<nAgg + nTr, 256, 0, stream>>>(x, dst, f1w, acc2g, Wt, nAgg);
    k_gemm<<<Bsz / BM, 256, 0, stream>>>(acc2g, Wt, cw, cb, f1b, f2w, f2b, out, Bsz);
}

// Round 7
// 78.299 us; speedup vs baseline: 4.2508x; 1.0175x over previous
//
#include <hip/hip_runtime.h>
#include <hip/hip_bf16.h>
#include <stdint.h>

#define NPG 28
#define KDIM 896
#define NOUT 256
#define BM 64
#define BK 32
#define KT (KDIM / BK)   // 28

typedef __attribute__((ext_vector_type(8))) __bf16 bf16x8;
typedef __attribute__((ext_vector_type(8))) ushort us8;
typedef __attribute__((ext_vector_type(4))) float f32x4;

__device__ __forceinline__ ushort f2bf(float v) {
    uint u = __float_as_uint(v);
    return (ushort)((u + 0x7fffu + ((u >> 16) & 1u)) >> 16);
}

__device__ __forceinline__ void gload_lds16(const void* g, void* l) {
    __builtin_amdgcn_global_load_lds(
        (const __attribute__((address_space(1))) void*)(uintptr_t)g,
        (__attribute__((address_space(3))) void*)(uintptr_t)l,
        16, 0, 0);
}

// ---------------- k_agg: atomic-free gather; acc2g written TRANSPOSED [j][graph] ----------------
// (k_gemm reads column kt for 64 consecutive graphs -> transposed layout makes that one
//  coalesced 512B load instead of a 64-line gather; round-3/6 were gather-latency-bound.)
__global__ __launch_bounds__(256) void k_agg(
    const float* __restrict__ x, const int* __restrict__ dst,
    const float* __restrict__ f1w,
    float* __restrict__ acc2g, ushort* __restrict__ wt, int nAgg)
{
    __shared__ int   pk[8][32];
    __shared__ float sx[8][32][2];
    __shared__ float t[32][33];

    const int tid = threadIdx.x;

    if ((int)blockIdx.x >= nAgg) {    // fc1_w transpose tiles
        int b = blockIdx.x - nAgg;
        int n0 = (b & 7) * 32, k0 = (b >> 3) * 32;
        int tx = tid & 31, ty = tid >> 5;
#pragma unroll
        for (int q = 0; q < 4; ++q)
            t[ty + q * 8][tx] = f1w[(k0 + ty + q * 8) * NOUT + n0 + tx];
        __syncthreads();
#pragma unroll
        for (int q = 0; q < 4; ++q)
            wt[(long)(n0 + ty + q * 8) * KDIM + k0 + tx] = f2bf(t[tx][ty + q * 8]);
        return;
    }

    const int g = tid >> 5;
    const int j = tid & 31;
    const long gb = ((long)blockIdx.x * 8 + g) * NPG;

    float2 xx = make_float2(0.f, 0.f);
    if (j < NPG) {
        int4 d4 = ((const int4*)dst)[gb + j];
        xx = ((const float2*)x)[gb + j];
        int gbi = (int)gb;
        pk[g][j] = (d4.x - gbi) | ((d4.y - gbi) << 8) |
                   ((d4.z - gbi) << 16) | ((d4.w - gbi) << 24);
    }
    __syncthreads();

    const uint repj = (uint)j * 0x01010101u;
    uint cp0 = 0, cp1 = 0, cp2 = 0, cp3 = 0;
    int cnt = 0;
#pragma unroll
    for (int s4 = 0; s4 < 7; ++s4) {
        int4 pv = *(const int4*)&pk[g][s4 * 4];
#pragma unroll
        for (int r = 0; r < 4; ++r) {
            uint v = ((const uint*)&pv)[r] ^ repj;
            uint zb = ~(((v & 0x7F7F7F7Fu) + 0x7F7F7F7Fu) | v) & 0x80808080u;
            uint c = (uint)__popc(zb);
            cnt += (int)c;
            int s = s4 * 4 + r;
            uint nib = c << ((s & 7) * 4);
            if (s < 8)       cp0 |= nib;
            else if (s < 16) cp1 |= nib;
            else if (s < 24) cp2 |= nib;
            else             cp3 |= nib;
        }
    }

    const float dinv = rsqrtf((float)(1 + cnt));
    const float sx0 = xx.x * dinv, sx1 = xx.y * dinv;
    if (j < NPG) {
        sx[g][j][0] = sx0;
        sx[g][j][1] = sx1;
    }
    __syncthreads();

    float a0 = sx0, a1 = sx1;
#pragma unroll
    for (int s = 0; s < NPG; ++s) {
        float2 sv = *(const float2*)&sx[g][s][0];
        uint cpw = (s < 8) ? cp0 : (s < 16) ? cp1 : (s < 24) ? cp2 : cp3;
        float cf = (float)((cpw >> ((s & 7) * 4)) & 0xFu);
        a0 += cf * sv.x;
        a1 += cf * sv.y;
    }

    if (j < NPG) {
        const long Btot = (long)nAgg * 8;
        const long graph = (long)blockIdx.x * 8 + g;
        ((float2*)acc2g)[(long)j * Btot + graph] = make_float2(a0 * dinv, a1 * dinv);
    }
}

// ---------------- k_gemm helpers ----------------
// Bs stage: wave w stages EXACTLY the rows it alone reads (w*64..w*64+63).
// LDS dest linear; global source granule pre-swizzled: phys = logical ^ ((row>>1)&3).
__device__ __forceinline__ void stage_b4(const char* WtB, ushort* BsX, int kt, int w, int l) {
    const int o = (l & 3) ^ ((l >> 3) & 3);
#pragma unroll
    for (int i = 0; i < 4; ++i) {
        int row = w * 64 + i * 16 + (l >> 2);
        gload_lds16(WtB + (long)row * (KDIM * 2) + kt * 64 + o * 16,
                    (char*)BsX + w * 4096 + i * 1024);
    }
}

// distributed A-gen: wave w generates feature-octet w of row l (one us8 -> ds_write_b128).
// Octet is wave-uniform -> conv weights live in SGPRs.
__device__ __forceinline__ void agen_write(ushort* AsX, float2 av, int awoff,
                                           const float* w0, const float* w1, const float* bb) {
    union { us8 v; uint u[4]; } pk;
#pragma unroll
    for (int k = 0; k < 4; ++k) {
        float e0 = fmaxf(av.x * w0[2 * k]     + av.y * w1[2 * k]     + bb[2 * k],     0.f);
        float e1 = fmaxf(av.x * w0[2 * k + 1] + av.y * w1[2 * k + 1] + bb[2 * k + 1], 0.f);
        __hip_bfloat162 h = __float22bfloat162_rn(make_float2(e0, e1));
        pk.u[k] = *reinterpret_cast<uint*>(&h);
    }
    *(us8*)&AsX[awoff] = pk.v;
}

// one K-step MFMA cluster: ds_read A/B fragments, 16 MFMAs (T5 around pure-MFMA region)
__device__ __forceinline__ void compute_mfma(const ushort* AsX, const ushort* BsX,
                                             f32x4 acc[4][4], int a_off, int b_off) {
    bf16x8 bfr[4], afr[4];
#pragma unroll
    for (int ni = 0; ni < 4; ++ni)
        bfr[ni] = *(const bf16x8*)(&BsX[b_off + ni * 512]);
#pragma unroll
    for (int mi = 0; mi < 4; ++mi)
        afr[mi] = *(const bf16x8*)(&AsX[a_off + mi * 512]);
    __builtin_amdgcn_s_setprio(1);
#pragma unroll
    for (int mi = 0; mi < 4; ++mi)
#pragma unroll
        for (int ni = 0; ni < 4; ++ni)
            acc[mi][ni] = __builtin_amdgcn_mfma_f32_16x16x32_bf16(
                afr[mi], bfr[ni], acc[mi][ni], 0, 0, 0);
    __builtin_amdgcn_s_setprio(0);
}

// ---------------- k_gemm: distributed A-gen, raw-barrier pipeline, coalesced A loads ----------------
// Barriers carry ONLY the LDS As hand-off (lgkmcnt(0) before s_barrier); each wave drains
// its own VMEM with vmcnt(0) AFTER the barrier.
__global__ __launch_bounds__(256, 3) void k_gemm(
    const float* __restrict__ acc2g, const ushort* __restrict__ Wt,
    const float* __restrict__ cw, const float* __restrict__ cb,
    const float* __restrict__ f1b, const float* __restrict__ f2w,
    const float* __restrict__ f2b, float* __restrict__ out, int Bsz)
{
    __shared__ ushort As0[BM * BK], As1[BM * BK];     // 2 x 4KB
    __shared__ ushort Bs0[NOUT * BK], Bs1[NOUT * BK]; // 2 x 16KB -> 40KB total

    const int tid = threadIdx.x;
    const int w = tid >> 6, l = tid & 63;
    const int l15 = l & 15, lhi = (l >> 4) & 3;
    const long m0 = (long)blockIdx.x * BM;
    const long Btot = Bsz;

    // A-gen role: wave w -> octet w (wave-uniform, SGPR weights), row l
    const int ao = __builtin_amdgcn_readfirstlane(w);
    const int awoff = l * 32 + ((ao ^ ((l >> 1) & 3)) * 8);
    float w0[8], w1[8], bb[8];
#pragma unroll
    for (int k = 0; k < 8; ++k) {
        w0[k] = cw[ao * 8 + k]; w1[k] = cw[32 + ao * 8 + k]; bb[k] = cb[ao * 8 + k];
    }

    const int swz = (lhi ^ ((l15 >> 1) & 3)) * 8;
    const int a_off = l15 * 32 + swz;                  // + mi*512
    const int b_off = (w * 64 + l15) * 32 + swz;       // + ni*512

    // transposed A: a2[kt*Btot + graph] -> lane l reads consecutive float2 (coalesced)
    const float2* a2 = (const float2*)acc2g;
    const char* WtB = (const char*)Wt;
    const long ag = m0 + l;

    f32x4 acc[4][4];
#pragma unroll
    for (int mi = 0; mi < 4; ++mi)
#pragma unroll
        for (int ni = 0; ni < 4; ++ni) acc[mi][ni] = (f32x4){0.f, 0.f, 0.f, 0.f};

    // prologue: A(0)->As0, Bs(0) staged, av(1) in flight; full drain once
    {
        float2 av0 = a2[ag];
        stage_b4(WtB, Bs0, 0, w, l);
        agen_write(As0, av0, awoff, w0, w1, bb);
    }
    float2 avn = a2[Btot + ag];
    __syncthreads();

    // steady loop: phases 0..25 (13 double-phases), peel 26/27
    for (int kt = 0; kt < KT - 2; kt += 2) {
        // phase kt (cur = buf0): build kt+1 into buf1
        stage_b4(WtB, Bs1, kt + 1, w, l);
        float2 avn2 = a2[(long)(kt + 2) * Btot + ag];
        agen_write(As1, avn, awoff, w0, w1, bb);
        compute_mfma(As0, Bs0, acc, a_off, b_off);
        asm volatile("s_waitcnt lgkmcnt(0)" ::: "memory"); // As1 writes + all ds_reads done
        __builtin_amdgcn_s_barrier();
        asm volatile("s_waitcnt vmcnt(0)" ::: "memory");   // own Bs1 stage (+av) drained, post-barrier

        // phase kt+1 (cur = buf1): build kt+2 into buf0
        stage_b4(WtB, Bs0, kt + 2, w, l);
        avn = a2[(long)(kt + 3) * Btot + ag];
        agen_write(As0, avn2, awoff, w0, w1, bb);
        compute_mfma(As1, Bs1, acc, a_off, b_off);
        asm volatile("s_waitcnt lgkmcnt(0)" ::: "memory");
        __builtin_amdgcn_s_barrier();
        asm volatile("s_waitcnt vmcnt(0)" ::: "memory");
    }
    // phase 26 (cur = buf0): build 27 into buf1
    {
        stage_b4(WtB, Bs1, KT - 1, w, l);
        agen_write(As1, avn, awoff, w0, w1, bb);
        compute_mfma(As0, Bs0, acc, a_off, b_off);
        asm volatile("s_waitcnt lgkmcnt(0)" ::: "memory");
        __builtin_amdgcn_s_barrier();
        asm volatile("s_waitcnt vmcnt(0)" ::: "memory");
        // phase 27
        compute_mfma(As1, Bs1, acc, a_off, b_off);
    }
    __syncthreads();   // protect As0 before reuse as reduction scratch

    // ---- fused epilogue: +bias, row L2-norm, FC2, sigmoid/softplus ----
    float b1[4], w20[4], w21[4];
#pragma unroll
    for (int ni = 0; ni < 4; ++ni) {
        int col = w * 64 + ni * 16 + l15;
        b1[ni] = f1b[col];
        w20[ni] = f2w[col * 2 + 0];
        w21[ni] = f2w[col * 2 + 1];
    }
    float* red    = (float*)As0;
    float* red_ss = red;             // [64][4]
    float* red_p0 = red + 256;
    float* red_p1 = red + 512;
    float* red_rn = red + 768;       // [64]

#pragma unroll
    for (int mi = 0; mi < 4; ++mi) {
        float ssr[4], p0r[4], p1r[4];
#pragma unroll
        for (int r = 0; r < 4; ++r) { ssr[r] = 0.f; p0r[r] = 0.f; p1r[r] = 0.f; }
#pragma unroll
        for (int ni = 0; ni < 4; ++ni) {
#pragma unroll
            for (int r = 0; r < 4; ++r) {
                float v = acc[mi][ni][r] + b1[ni];
                acc[mi][ni][r] = v;
                ssr[r] += v * v;
                p0r[r] += v * w20[ni];
                p1r[r] += v * w21[ni];
            }
        }
#pragma unroll
        for (int m = 1; m < 16; m <<= 1) {
#pragma unroll
            for (int r = 0; r < 4; ++r) {
                ssr[r] += __shfl_xor(ssr[r], m);
                p0r[r] += __shfl_xor(p0r[r], m);
                p1r[r] += __shfl_xor(p1r[r], m);
            }
        }
        if (l15 == 0) {
            int rowb = mi * 16 + lhi * 4;
#pragma unroll
            for (int r = 0; r < 4; ++r) {
                red_ss[(rowb + r) * 4 + w] = ssr[r];
                red_p0[(rowb + r) * 4 + w] = p0r[r];
                red_p1[(rowb + r) * 4 + w] = p1r[r];
            }
        }
    }
    __syncthreads();

    if (tid < BM) {
        int row = tid;
        float ss = red_ss[row * 4 + 0] + red_ss[row * 4 + 1] + red_ss[row * 4 + 2] + red_ss[row * 4 + 3];
        float p0 = red_p0[row * 4 + 0] + red_p0[row * 4 + 1] + red_p0[row * 4 + 2] + red_p0[row * 4 + 3];
        float p1 = red_p1[row * 4 + 0] + red_p1[row * 4 + 1] + red_p1[row * 4 + 2] + red_p1[row * 4 + 3];
        float rn = 1.0f / fmaxf(sqrtf(ss), 1e-12f);
        float x0 = p0 * rn + f2b[0];
        float x1 = p1 * rn + f2b[1];
        float mu = 1.0f / (1.0f + expf(-x0));
        float th = (x1 > 0.f) ? (x1 + log1pf(expf(-x1))) : log1pf(expf(x1));
        long gr = m0 + row;
        out[(long)Bsz * NOUT + gr] = mu;
        out[(long)Bsz * NOUT + Bsz + gr] = th;
        red_rn[row] = rn;
    }
    __syncthreads();

#pragma unroll
    for (int mi = 0; mi < 4; ++mi) {
        float rn[4];
#pragma unroll
        for (int r = 0; r < 4; ++r) rn[r] = red_rn[mi * 16 + lhi * 4 + r];
#pragma unroll
        for (int ni = 0; ni < 4; ++ni) {
#pragma unroll
            for (int r = 0; r < 4; ++r) {
                long row = m0 + mi * 16 + lhi * 4 + r;
                out[row * NOUT + w * 64 + ni * 16 + l15] = acc[mi][ni][r] * rn[r];
            }
        }
    }
}

extern "C" void kernel_launch(void* const* d_in, const int* in_sizes, int n_in,
                              void* d_out, int out_size, void* d_ws, size_t ws_size,
                              hipStream_t stream) {
    const float* x   = (const float*)d_in[0];
    const int*   ei  = (const int*)d_in[1];
    const float* cw  = (const float*)d_in[2];
    const float* cb  = (const float*)d_in[3];
    const float* f1w = (const float*)d_in[4];
    const float* f1b = (const float*)d_in[5];
    const float* f2w = (const float*)d_in[6];
    const float* f2b = (const float*)d_in[7];
    float* out = (float*)d_out;

    const int Nn  = in_sizes[0] / 2;       // nodes
    const int Bsz = Nn / NPG;              // graphs
    const int E   = in_sizes[1] / 2;       // edges
    const int* dst = ei + E;

    float*  acc2g = (float*)d_ws;                      // [NPG][Bsz] f32x2 (transposed)
    ushort* Wt    = (ushort*)(acc2g + (size_t)Nn * 2); // [256][896] bf16

    const int nAgg = Bsz / 8;                          // 8192 (8 graphs per block)
    const int nTr  = (KDIM / 32) * (NOUT / 32);        // 224

    k_agg<<<nAgg + nTr, 256, 0, stream>>>(x, dst, f1w, acc2g, Wt, nAgg);
    k_gemm<<<Bsz / BM, 256, 0, stream>>>(acc2g, Wt, cw, cb, f1b, f2w, f2b, out, Bsz);
}

// Round 8
// 67.685 us; speedup vs baseline: 4.9174x; 1.1568x over previous
//
#include <hip/hip_runtime.h>
#include <hip/hip_bf16.h>
#include <stdint.h>

#define NPG 28
#define KDIM 896
#define NOUT 256
#define BM 128
#define BK 32
#define KT (KDIM / BK)   // 28

typedef __attribute__((ext_vector_type(8))) __bf16 bf16x8;
typedef __attribute__((ext_vector_type(8))) ushort us8;
typedef __attribute__((ext_vector_type(4))) float f32x4;

__device__ __forceinline__ ushort f2bf(float v) {
    uint u = __float_as_uint(v);
    return (ushort)((u + 0x7fffu + ((u >> 16) & 1u)) >> 16);
}

__device__ __forceinline__ void gload_lds16(const void* g, void* l) {
    __builtin_amdgcn_global_load_lds(
        (const __attribute__((address_space(1))) void*)(uintptr_t)g,
        (__attribute__((address_space(3))) void*)(uintptr_t)l,
        16, 0, 0);
}

// ---------------- k_agg ----------------
// acc2g written TRANSPOSED [j][graph] (coalesced per-phase A loads in k_gemm).
// Wt written PHASE-TILED [kt][256][32] bf16: each phase's 16KB B-tile contiguous in
// global -> k_gemm stage reads are 1KB-contiguous per gload_lds (round-7 was a
// 16-line scatter per instruction; B-staging L2 traffic was the bottleneck).
__global__ __launch_bounds__(256) void k_agg(
    const float* __restrict__ x, const int* __restrict__ dst,
    const float* __restrict__ f1w,
    float* __restrict__ acc2g, ushort* __restrict__ wt, int nAgg)
{
    __shared__ int   pk[8][32];
    __shared__ float sx[8][32][2];
    __shared__ float t[32][33];

    const int tid = threadIdx.x;

    if ((int)blockIdx.x >= nAgg) {    // fc1_w transpose tiles
        int b = blockIdx.x - nAgg;
        int n0 = (b & 7) * 32, k0 = (b >> 3) * 32;
        int tx = tid & 31, ty = tid >> 5;
#pragma unroll
        for (int q = 0; q < 4; ++q)
            t[ty + q * 8][tx] = f1w[(k0 + ty + q * 8) * NOUT + n0 + tx];
        __syncthreads();
        // wt[kt][n][kk]: kt = k0/32, n = n0+ty+q*8, kk = tx
#pragma unroll
        for (int q = 0; q < 4; ++q)
            wt[(long)(k0 >> 5) * (NOUT * BK) + (n0 + ty + q * 8) * BK + tx] =
                f2bf(t[tx][ty + q * 8]);
        return;
    }

    const int g = tid >> 5;
    const int j = tid & 31;
    const long gb = ((long)blockIdx.x * 8 + g) * NPG;

    float2 xx = make_float2(0.f, 0.f);
    if (j < NPG) {
        int4 d4 = ((const int4*)dst)[gb + j];
        xx = ((const float2*)x)[gb + j];
        int gbi = (int)gb;
        pk[g][j] = (d4.x - gbi) | ((d4.y - gbi) << 8) |
                   ((d4.z - gbi) << 16) | ((d4.w - gbi) << 24);
    }
    __syncthreads();

    const uint repj = (uint)j * 0x01010101u;
    uint cp0 = 0, cp1 = 0, cp2 = 0, cp3 = 0;
    int cnt = 0;
#pragma unroll
    for (int s4 = 0; s4 < 7; ++s4) {
        int4 pv = *(const int4*)&pk[g][s4 * 4];
#pragma unroll
        for (int r = 0; r < 4; ++r) {
            uint v = ((const uint*)&pv)[r] ^ repj;
            uint zb = ~(((v & 0x7F7F7F7Fu) + 0x7F7F7F7Fu) | v) & 0x80808080u;
            uint c = (uint)__popc(zb);
            cnt += (int)c;
            int s = s4 * 4 + r;
            uint nib = c << ((s & 7) * 4);
            if (s < 8)       cp0 |= nib;
            else if (s < 16) cp1 |= nib;
            else if (s < 24) cp2 |= nib;
            else             cp3 |= nib;
        }
    }

    const float dinv = rsqrtf((float)(1 + cnt));
    const float sx0 = xx.x * dinv, sx1 = xx.y * dinv;
    if (j < NPG) {
        sx[g][j][0] = sx0;
        sx[g][j][1] = sx1;
    }
    __syncthreads();

    float a0 = sx0, a1 = sx1;
#pragma unroll
    for (int s = 0; s < NPG; ++s) {
        float2 sv = *(const float2*)&sx[g][s][0];
        uint cpw = (s < 8) ? cp0 : (s < 16) ? cp1 : (s < 24) ? cp2 : cp3;
        float cf = (float)((cpw >> ((s & 7) * 4)) & 0xFu);
        a0 += cf * sv.x;
        a1 += cf * sv.y;
    }

    if (j < NPG) {
        const long Btot = (long)nAgg * 8;
        const long graph = (long)blockIdx.x * 8 + g;
        ((float2*)acc2g)[(long)j * Btot + graph] = make_float2(a0 * dinv, a1 * dinv);
    }
}

// ---------------- k_gemm helpers (BM=128, 4 waves, wave-tile 128x64) ----------------
// Bs stage from phase-tiled Wt: tile kt at byte offset kt*16384; row (=col n) stride 64B.
// Each gload_lds: 16 consecutive rows x 64B = 1KB CONTIGUOUS. Source granule pre-swizzled
// (phys = logical ^ ((row>>1)&3)); LDS dest linear. Wave w stages exactly its own rows.
__device__ __forceinline__ void stage_b4(const char* WtB, ushort* BsX, int kt, int w, int l) {
    const int o = (l & 3) ^ ((l >> 3) & 3);
#pragma unroll
    for (int i = 0; i < 4; ++i) {
        int row = w * 64 + i * 16 + (l >> 2);
        gload_lds16(WtB + (long)kt * 16384 + row * 64 + o * 16,
                    (char*)BsX + w * 4096 + i * 1024);
    }
}

// distributed A-gen: wave w -> feature-octet w (SGPR weights); thread covers rows l, l+64.
__device__ __forceinline__ void agen_write(ushort* AsX, float2 av, int awoff,
                                           const float* w0, const float* w1, const float* bb) {
    union { us8 v; uint u[4]; } pk;
#pragma unroll
    for (int k = 0; k < 4; ++k) {
        float e0 = fmaxf(av.x * w0[2 * k]     + av.y * w1[2 * k]     + bb[2 * k],     0.f);
        float e1 = fmaxf(av.x * w0[2 * k + 1] + av.y * w1[2 * k + 1] + bb[2 * k + 1], 0.f);
        __hip_bfloat162 h = __float22bfloat162_rn(make_float2(e0, e1));
        pk.u[k] = *reinterpret_cast<uint*>(&h);
    }
    *(us8*)&AsX[awoff] = pk.v;
}

// one K-step MFMA cluster: 8x4 = 32 MFMAs per wave
__device__ __forceinline__ void compute_mfma(const ushort* AsX, const ushort* BsX,
                                             f32x4 acc[8][4], int a_off, int b_off) {
    bf16x8 bfr[4];
#pragma unroll
    for (int ni = 0; ni < 4; ++ni)
        bfr[ni] = *(const bf16x8*)(&BsX[b_off + ni * 512]);
    __builtin_amdgcn_s_setprio(1);
#pragma unroll
    for (int mi = 0; mi < 8; ++mi) {
        bf16x8 af = *(const bf16x8*)(&AsX[a_off + mi * 512]);
#pragma unroll
        for (int ni = 0; ni < 4; ++ni)
            acc[mi][ni] = __builtin_amdgcn_mfma_f32_16x16x32_bf16(
                af, bfr[ni], acc[mi][ni], 0, 0, 0);
    }
    __builtin_amdgcn_s_setprio(0);
}

// ---------------- k_gemm: BM=128, 4 waves, (256,2) -> exactly 2 blocks/CU, grid 512 ----------------
// Pipeline discipline (verified round 7): lgkmcnt(0) -> s_barrier -> vmcnt(0).
__global__ __launch_bounds__(256, 2) void k_gemm(
    const float* __restrict__ acc2g, const ushort* __restrict__ Wt,
    const float* __restrict__ cw, const float* __restrict__ cb,
    const float* __restrict__ f1b, const float* __restrict__ f2w,
    const float* __restrict__ f2b, float* __restrict__ out, int Bsz)
{
    __shared__ ushort As0[BM * BK], As1[BM * BK];     // 2 x 8KB
    __shared__ ushort Bs0[NOUT * BK], Bs1[NOUT * BK]; // 2 x 16KB -> 48KB total

    const int tid = threadIdx.x;
    const int w = tid >> 6, l = tid & 63;
    const int l15 = l & 15, lhi = (l >> 4) & 3;
    const long m0 = (long)blockIdx.x * BM;
    const long Btot = Bsz;

    // A-gen role: wave w -> octet w (wave-uniform, SGPR weights); rows l and l+64
    const int ao = __builtin_amdgcn_readfirstlane(w);
    const int axor = (ao ^ ((l >> 1) & 3)) * 8;        // same for l and l+64
    const int awoff_lo = l * 32 + axor;
    const int awoff_hi = (l + 64) * 32 + axor;
    float w0[8], w1[8], bb[8];
#pragma unroll
    for (int k = 0; k < 8; ++k) {
        w0[k] = cw[ao * 8 + k]; w1[k] = cw[32 + ao * 8 + k]; bb[k] = cb[ao * 8 + k];
    }

    const int swz = (lhi ^ ((l15 >> 1) & 3)) * 8;
    const int a_off = l15 * 32 + swz;                  // + mi*512, mi=0..7
    const int b_off = (w * 64 + l15) * 32 + swz;       // + ni*512

    const float2* a2 = (const float2*)acc2g;           // transposed [kt][graph]
    const char* WtB = (const char*)Wt;                 // phase-tiled [kt][256][32]
    const long ag = m0 + l;

    f32x4 acc[8][4];
#pragma unroll
    for (int mi = 0; mi < 8; ++mi)
#pragma unroll
        for (int ni = 0; ni < 4; ++ni) acc[mi][ni] = (f32x4){0.f, 0.f, 0.f, 0.f};

    // prologue: A(0)->As0, Bs(0) staged; full drain once
    {
        float2 alo = a2[ag];
        float2 ahi = a2[ag + 64];
        stage_b4(WtB, Bs0, 0, w, l);
        agen_write(As0, alo, awoff_lo, w0, w1, bb);
        agen_write(As0, ahi, awoff_hi, w0, w1, bb);
    }
    float2 nlo = a2[Btot + ag], nhi = a2[Btot + ag + 64];
    __syncthreads();

    // steady loop: phases 0..25 (13 double-phases), peel 26/27
    for (int kt = 0; kt < KT - 2; kt += 2) {
        // phase kt (cur = buf0): build kt+1 into buf1
        stage_b4(WtB, Bs1, kt + 1, w, l);
        float2 n2lo = a2[(long)(kt + 2) * Btot + ag];
        float2 n2hi = a2[(long)(kt + 2) * Btot + ag + 64];
        agen_write(As1, nlo, awoff_lo, w0, w1, bb);
        agen_write(As1, nhi, awoff_hi, w0, w1, bb);
        compute_mfma(As0, Bs0, acc, a_off, b_off);
        asm volatile("s_waitcnt lgkmcnt(0)" ::: "memory");
        __builtin_amdgcn_s_barrier();
        asm volatile("s_waitcnt vmcnt(0)" ::: "memory");

        // phase kt+1 (cur = buf1): build kt+2 into buf0
        stage_b4(WtB, Bs0, kt + 2, w, l);
        nlo = a2[(long)(kt + 3) * Btot + ag];
        nhi = a2[(long)(kt + 3) * Btot + ag + 64];
        agen_write(As0, n2lo, awoff_lo, w0, w1, bb);
        agen_write(As0, n2hi, awoff_hi, w0, w1, bb);
        compute_mfma(As1, Bs1, acc, a_off, b_off);
        asm volatile("s_waitcnt lgkmcnt(0)" ::: "memory");
        __builtin_amdgcn_s_barrier();
        asm volatile("s_waitcnt vmcnt(0)" ::: "memory");
    }
    // phase 26 (cur = buf0): build 27 into buf1
    {
        stage_b4(WtB, Bs1, KT - 1, w, l);
        agen_write(As1, nlo, awoff_lo, w0, w1, bb);
        agen_write(As1, nhi, awoff_hi, w0, w1, bb);
        compute_mfma(As0, Bs0, acc, a_off, b_off);
        asm volatile("s_waitcnt lgkmcnt(0)" ::: "memory");
        __builtin_amdgcn_s_barrier();
        asm volatile("s_waitcnt vmcnt(0)" ::: "memory");
        // phase 27
        compute_mfma(As1, Bs1, acc, a_off, b_off);
    }
    __syncthreads();   // Bs0 dead (last read phase 26) -> reuse as reduction scratch

    // ---- fused epilogue: +bias, row L2-norm, FC2, sigmoid/softplus ----
    float b1[4], w20[4], w21[4];
#pragma unroll
    for (int ni = 0; ni < 4; ++ni) {
        int col = w * 64 + ni * 16 + l15;
        b1[ni] = f1b[col];
        w20[ni] = f2w[col * 2 + 0];
        w21[ni] = f2w[col * 2 + 1];
    }
    float* red    = (float*)Bs0;     // 16KB scratch
    float* red_ss = red;             // [128][4]
    float* red_p0 = red + 512;
    float* red_p1 = red + 1024;
    float* red_rn = red + 1536;      // [128]

#pragma unroll
    for (int mi = 0; mi < 8; ++mi) {
        float ssr[4], p0r[4], p1r[4];
#pragma unroll
        for (int r = 0; r < 4; ++r) { ssr[r] = 0.f; p0r[r] = 0.f; p1r[r] = 0.f; }
#pragma unroll
        for (int ni = 0; ni < 4; ++ni) {
#pragma unroll
            for (int r = 0; r < 4; ++r) {
                float v = acc[mi][ni][r] + b1[ni];
                acc[mi][ni][r] = v;
                ssr[r] += v * v;
                p0r[r] += v * w20[ni];
                p1r[r] += v * w21[ni];
            }
        }
#pragma unroll
        for (int m = 1; m < 16; m <<= 1) {
#pragma unroll
            for (int r = 0; r < 4; ++r) {
                ssr[r] += __shfl_xor(ssr[r], m);
                p0r[r] += __shfl_xor(p0r[r], m);
                p1r[r] += __shfl_xor(p1r[r], m);
            }
        }
        if (l15 == 0) {
            int rowb = mi * 16 + lhi * 4;
#pragma unroll
            for (int r = 0; r < 4; ++r) {
                red_ss[(rowb + r) * 4 + w] = ssr[r];
                red_p0[(rowb + r) * 4 + w] = p0r[r];
                red_p1[(rowb + r) * 4 + w] = p1r[r];
            }
        }
    }
    __syncthreads();

    if (tid < BM) {
        int row = tid;
        float ss = red_ss[row * 4 + 0] + red_ss[row * 4 + 1] + red_ss[row * 4 + 2] + red_ss[row * 4 + 3];
        float p0 = red_p0[row * 4 + 0] + red_p0[row * 4 + 1] + red_p0[row * 4 + 2] + red_p0[row * 4 + 3];
        float p1 = red_p1[row * 4 + 0] + red_p1[row * 4 + 1] + red_p1[row * 4 + 2] + red_p1[row * 4 + 3];
        float rn = 1.0f / fmaxf(sqrtf(ss), 1e-12f);
        float x0 = p0 * rn + f2b[0];
        float x1 = p1 * rn + f2b[1];
        float mu = 1.0f / (1.0f + expf(-x0));
        float th = (x1 > 0.f) ? (x1 + log1pf(expf(-x1))) : log1pf(expf(x1));
        long gr = m0 + row;
        out[(long)Bsz * NOUT + gr] = mu;
        out[(long)Bsz * NOUT + Bsz + gr] = th;
        red_rn[row] = rn;
    }
    __syncthreads();

#pragma unroll
    for (int mi = 0; mi < 8; ++mi) {
        float rn[4];
#pragma unroll
        for (int r = 0; r < 4; ++r) rn[r] = red_rn[mi * 16 + lhi * 4 + r];
#pragma unroll
        for (int ni = 0; ni < 4; ++ni) {
#pragma unroll
            for (int r = 0; r < 4; ++r) {
                long row = m0 + mi * 16 + lhi * 4 + r;
                out[row * NOUT + w * 64 + ni * 16 + l15] = acc[mi][ni][r] * rn[r];
            }
        }
    }
}

extern "C" void kernel_launch(void* const* d_in, const int* in_sizes, int n_in,
                              void* d_out, int out_size, void* d_ws, size_t ws_size,
                              hipStream_t stream) {
    const float* x   = (const float*)d_in[0];
    const int*   ei  = (const int*)d_in[1];
    const float* cw  = (const float*)d_in[2];
    const float* cb  = (const float*)d_in[3];
    const float* f1w = (const float*)d_in[4];
    const float* f1b = (const float*)d_in[5];
    const float* f2w = (const float*)d_in[6];
    const float* f2b = (const float*)d_in[7];
    float* out = (float*)d_out;

    const int Nn  = in_sizes[0] / 2;       // nodes
    const int Bsz = Nn / NPG;              // graphs
    const int E   = in_sizes[1] / 2;       // edges
    const int* dst = ei + E;

    float*  acc2g = (float*)d_ws;                      // [NPG][Bsz] f32x2 (transposed)
    ushort* Wt    = (ushort*)(acc2g + (size_t)Nn * 2); // [28][256][32] bf16 (phase-tiled)

    const int nAgg = Bsz / 8;                          // 8192 (8 graphs per block)
    const int nTr  = (KDIM / 32) * (NOUT / 32);        // 224

    k_agg<<<nAgg + nTr, 256, 0, stream>>>(x, dst, f1w, acc2g, Wt, nAgg);
    k_gemm<<<Bsz / BM, 256, 0, stream>>>(acc2g, Wt, cw, cb, f1b, f2w, f2b, out, Bsz);
}

// Round 9
// 67.580 us; speedup vs baseline: 4.9250x; 1.0016x over previous
//
#include <hip/hip_runtime.h>
#include <hip/hip_bf16.h>
#include <stdint.h>

#define NPG 28
#define KDIM 896
#define NOUT 256
#define BM 128
#define BK 32
#define KT (KDIM / BK)   // 28

typedef __attribute__((ext_vector_type(8))) __bf16 bf16x8;
typedef __attribute__((ext_vector_type(8))) ushort us8;
typedef __attribute__((ext_vector_type(4))) float f32x4;

__device__ __forceinline__ ushort f2bf(float v) {
    uint u = __float_as_uint(v);
    return (ushort)((u + 0x7fffu + ((u >> 16) & 1u)) >> 16);
}

__device__ __forceinline__ void gload_lds16(const void* g, void* l) {
    __builtin_amdgcn_global_load_lds(
        (const __attribute__((address_space(1))) void*)(uintptr_t)g,
        (__attribute__((address_space(3))) void*)(uintptr_t)l,
        16, 0, 0);
}

// ---------------- k_agg (unchanged from round 8) ----------------
// acc2g TRANSPOSED [j][graph]; Wt PHASE-TILED [kt][256][32] bf16.
__global__ __launch_bounds__(256) void k_agg(
    const float* __restrict__ x, const int* __restrict__ dst,
    const float* __restrict__ f1w,
    float* __restrict__ acc2g, ushort* __restrict__ wt, int nAgg)
{
    __shared__ int   pk[8][32];
    __shared__ float sx[8][32][2];
    __shared__ float t[32][33];

    const int tid = threadIdx.x;

    if ((int)blockIdx.x >= nAgg) {    // fc1_w transpose tiles
        int b = blockIdx.x - nAgg;
        int n0 = (b & 7) * 32, k0 = (b >> 3) * 32;
        int tx = tid & 31, ty = tid >> 5;
#pragma unroll
        for (int q = 0; q < 4; ++q)
            t[ty + q * 8][tx] = f1w[(k0 + ty + q * 8) * NOUT + n0 + tx];
        __syncthreads();
#pragma unroll
        for (int q = 0; q < 4; ++q)
            wt[(long)(k0 >> 5) * (NOUT * BK) + (n0 + ty + q * 8) * BK + tx] =
                f2bf(t[tx][ty + q * 8]);
        return;
    }

    const int g = tid >> 5;
    const int j = tid & 31;
    const long gb = ((long)blockIdx.x * 8 + g) * NPG;

    float2 xx = make_float2(0.f, 0.f);
    if (j < NPG) {
        int4 d4 = ((const int4*)dst)[gb + j];
        xx = ((const float2*)x)[gb + j];
        int gbi = (int)gb;
        pk[g][j] = (d4.x - gbi) | ((d4.y - gbi) << 8) |
                   ((d4.z - gbi) << 16) | ((d4.w - gbi) << 24);
    }
    __syncthreads();

    const uint repj = (uint)j * 0x01010101u;
    uint cp0 = 0, cp1 = 0, cp2 = 0, cp3 = 0;
    int cnt = 0;
#pragma unroll
    for (int s4 = 0; s4 < 7; ++s4) {
        int4 pv = *(const int4*)&pk[g][s4 * 4];
#pragma unroll
        for (int r = 0; r < 4; ++r) {
            uint v = ((const uint*)&pv)[r] ^ repj;
            uint zb = ~(((v & 0x7F7F7F7Fu) + 0x7F7F7F7Fu) | v) & 0x80808080u;
            uint c = (uint)__popc(zb);
            cnt += (int)c;
            int s = s4 * 4 + r;
            uint nib = c << ((s & 7) * 4);
            if (s < 8)       cp0 |= nib;
            else if (s < 16) cp1 |= nib;
            else if (s < 24) cp2 |= nib;
            else             cp3 |= nib;
        }
    }

    const float dinv = rsqrtf((float)(1 + cnt));
    const float sx0 = xx.x * dinv, sx1 = xx.y * dinv;
    if (j < NPG) {
        sx[g][j][0] = sx0;
        sx[g][j][1] = sx1;
    }
    __syncthreads();

    float a0 = sx0, a1 = sx1;
#pragma unroll
    for (int s = 0; s < NPG; ++s) {
        float2 sv = *(const float2*)&sx[g][s][0];
        uint cpw = (s < 8) ? cp0 : (s < 16) ? cp1 : (s < 24) ? cp2 : cp3;
        float cf = (float)((cpw >> ((s & 7) * 4)) & 0xFu);
        a0 += cf * sv.x;
        a1 += cf * sv.y;
    }

    if (j < NPG) {
        const long Btot = (long)nAgg * 8;
        const long graph = (long)blockIdx.x * 8 + g;
        ((float2*)acc2g)[(long)j * Btot + graph] = make_float2(a0 * dinv, a1 * dinv);
    }
}

// ---------------- k_gemm helpers (BM=128, 8 waves 2Mx4N, wave-tile 64x64) ----------------
// Bs stage (512 threads, 16KB tile): 2 gload_lds per thread, 1KB-contiguous spans.
// LDS linear dest [row][32] with octet-XOR; source granule pre-swizzled
// o = (tid&3)^((tid>>3)&3)  (phys = logical ^ ((row>>1)&3), row = tid>>2 (+128)).
__device__ __forceinline__ void stage_b2(const char* WtB, ushort* BsX, int kt, int tid) {
    const int o = (tid & 3) ^ ((tid >> 3) & 3);
    const long tb = (long)kt * 16384 + (tid >> 2) * 64 + o * 16;
    gload_lds16(WtB + tb,        (char*)BsX + tid * 16);
    gload_lds16(WtB + tb + 8192, (char*)BsX + 8192 + tid * 16);
}

// distributed A-gen: wave w -> octet w&3 (SGPR weights), row (w>>2)*64 + l. One us8/thread.
__device__ __forceinline__ void agen_write(ushort* AsX, float2 av, int awoff,
                                           const float* w0, const float* w1, const float* bb) {
    union { us8 v; uint u[4]; } pk;
#pragma unroll
    for (int k = 0; k < 4; ++k) {
        float e0 = fmaxf(av.x * w0[2 * k]     + av.y * w1[2 * k]     + bb[2 * k],     0.f);
        float e1 = fmaxf(av.x * w0[2 * k + 1] + av.y * w1[2 * k + 1] + bb[2 * k + 1], 0.f);
        __hip_bfloat162 h = __float22bfloat162_rn(make_float2(e0, e1));
        pk.u[k] = *reinterpret_cast<uint*>(&h);
    }
    *(us8*)&AsX[awoff] = pk.v;
}

// one K-step MFMA cluster per wave: 4x4 = 16 MFMAs on its 64x64 sub-tile
__device__ __forceinline__ void compute_mfma(const ushort* AsX, const ushort* BsX,
                                             f32x4 acc[4][4], int a_off, int b_off) {
    bf16x8 bfr[4], afr[4];
#pragma unroll
    for (int ni = 0; ni < 4; ++ni)
        bfr[ni] = *(const bf16x8*)(&BsX[b_off + ni * 512]);
#pragma unroll
    for (int mi = 0; mi < 4; ++mi)
        afr[mi] = *(const bf16x8*)(&AsX[a_off + mi * 512]);
    __builtin_amdgcn_s_setprio(1);
#pragma unroll
    for (int mi = 0; mi < 4; ++mi)
#pragma unroll
        for (int ni = 0; ni < 4; ++ni)
            acc[mi][ni] = __builtin_amdgcn_mfma_f32_16x16x32_bf16(
                afr[mi], bfr[ni], acc[mi][ni], 0, 0, 0);
    __builtin_amdgcn_s_setprio(0);
}

// ---------------- k_gemm: BM=128, 8 waves, (512,3) -> 16 waves/CU (4/SIMD) ----------------
__global__ __launch_bounds__(512, 3) void k_gemm(
    const float* __restrict__ acc2g, const ushort* __restrict__ Wt,
    const float* __restrict__ cw, const float* __restrict__ cb,
    const float* __restrict__ f1b, const float* __restrict__ f2w,
    const float* __restrict__ f2b, float* __restrict__ out, int Bsz)
{
    __shared__ ushort As0[BM * BK], As1[BM * BK];     // 2 x 8KB
    __shared__ ushort Bs0[NOUT * BK], Bs1[NOUT * BK]; // 2 x 16KB -> 48KB total

    const int tid = threadIdx.x;
    const int w = tid >> 6, l = tid & 63;
    const int wM = w >> 2, wN = w & 3;
    const int l15 = l & 15, lhi = (l >> 4) & 3;
    const long m0 = (long)blockIdx.x * BM;
    const long Btot = Bsz;

    // A-gen role: octet = w&3 (wave-uniform -> SGPR weights), row = (w>>2)*64 + l
    const int ao = __builtin_amdgcn_readfirstlane(w & 3);
    const int arow = (w >> 2) * 64 + l;
    const int awoff = arow * 32 + ((ao ^ ((l >> 1) & 3)) * 8);
    float w0[8], w1[8], bb[8];
#pragma unroll
    for (int k = 0; k < 8; ++k) {
        w0[k] = cw[ao * 8 + k]; w1[k] = cw[32 + ao * 8 + k]; bb[k] = cb[ao * 8 + k];
    }

    const int swz = (lhi ^ ((l15 >> 1) & 3)) * 8;
    const int a_off = (wM * 64 + l15) * 32 + swz;      // + mi*512
    const int b_off = (wN * 64 + l15) * 32 + swz;      // + ni*512

    const float2* a2 = (const float2*)acc2g;           // transposed [kt][graph]
    const char* WtB = (const char*)Wt;                 // phase-tiled [kt][256][32]
    const long ag = m0 + arow;                         // per-wave coalesced 512B

    f32x4 acc[4][4];
#pragma unroll
    for (int mi = 0; mi < 4; ++mi)
#pragma unroll
        for (int ni = 0; ni < 4; ++ni) acc[mi][ni] = (f32x4){0.f, 0.f, 0.f, 0.f};

    // prologue
    {
        float2 av0 = a2[ag];
        stage_b2(WtB, Bs0, 0, tid);
        agen_write(As0, av0, awoff, w0, w1, bb);
    }
    float2 avn = a2[Btot + ag];
    __syncthreads();

    for (int kt = 0; kt < KT; kt += 2) {
        // phase kt (cur = buf0): build kt+1 into buf1
        stage_b2(WtB, Bs1, kt + 1, tid);
        float2 avn2 = (kt + 2 < KT) ? a2[(long)(kt + 2) * Btot + ag] : make_float2(0.f, 0.f);
        agen_write(As1, avn, awoff, w0, w1, bb);
        compute_mfma(As0, Bs0, acc, a_off, b_off);
        __syncthreads();

        // phase kt+1 (cur = buf1): build kt+2 into buf0
        if (kt + 2 < KT) {
            stage_b2(WtB, Bs0, kt + 2, tid);
            avn = a2[(long)(kt + 3) * Btot + ag];
            agen_write(As0, avn2, awoff, w0, w1, bb);
        }
        compute_mfma(As1, Bs1, acc, a_off, b_off);
        __syncthreads();
    }

    // ---- fused epilogue: +bias, row L2-norm, FC2, sigmoid/softplus ----
    float b1[4], w20[4], w21[4];
#pragma unroll
    for (int ni = 0; ni < 4; ++ni) {
        int col = wN * 64 + ni * 16 + l15;
        b1[ni] = f1b[col];
        w20[ni] = f2w[col * 2 + 0];
        w21[ni] = f2w[col * 2 + 1];
    }
    float* red    = (float*)As0;     // 8KB scratch (As0 dead after final barrier)
    float* red_ss = red;             // [128][4]
    float* red_p0 = red + 512;
    float* red_p1 = red + 1024;
    float* red_rn = red + 1536;      // [128]

#pragma unroll
    for (int mi = 0; mi < 4; ++mi) {
        float ssr[4], p0r[4], p1r[4];
#pragma unroll
        for (int r = 0; r < 4; ++r) { ssr[r] = 0.f; p0r[r] = 0.f; p1r[r] = 0.f; }
#pragma unroll
        for (int ni = 0; ni < 4; ++ni) {
#pragma unroll
            for (int r = 0; r < 4; ++r) {
                float v = acc[mi][ni][r] + b1[ni];
                acc[mi][ni][r] = v;
                ssr[r] += v * v;
                p0r[r] += v * w20[ni];
                p1r[r] += v * w21[ni];
            }
        }
#pragma unroll
        for (int m = 1; m < 16; m <<= 1) {
#pragma unroll
            for (int r = 0; r < 4; ++r) {
                ssr[r] += __shfl_xor(ssr[r], m);
                p0r[r] += __shfl_xor(p0r[r], m);
                p1r[r] += __shfl_xor(p1r[r], m);
            }
        }
        if (l15 == 0) {
            int rowb = wM * 64 + mi * 16 + lhi * 4;
#pragma unroll
            for (int r = 0; r < 4; ++r) {
                red_ss[(rowb + r) * 4 + wN] = ssr[r];
                red_p0[(rowb + r) * 4 + wN] = p0r[r];
                red_p1[(rowb + r) * 4 + wN] = p1r[r];
            }
        }
    }
    __syncthreads();

    if (tid < BM) {
        int row = tid;
        float ss = red_ss[row * 4 + 0] + red_ss[row * 4 + 1] + red_ss[row * 4 + 2] + red_ss[row * 4 + 3];
        float p0 = red_p0[row * 4 + 0] + red_p0[row * 4 + 1] + red_p0[row * 4 + 2] + red_p0[row * 4 + 3];
        float p1 = red_p1[row * 4 + 0] + red_p1[row * 4 + 1] + red_p1[row * 4 + 2] + red_p1[row * 4 + 3];
        float rn = 1.0f / fmaxf(sqrtf(ss), 1e-12f);
        float x0 = p0 * rn + f2b[0];
        float x1 = p1 * rn + f2b[1];
        float mu = 1.0f / (1.0f + expf(-x0));
        float th = (x1 > 0.f) ? (x1 + log1pf(expf(-x1))) : log1pf(expf(x1));
        long gr = m0 + row;
        out[(long)Bsz * NOUT + gr] = mu;
        out[(long)Bsz * NOUT + Bsz + gr] = th;
        red_rn[row] = rn;
    }
    __syncthreads();

#pragma unroll
    for (int mi = 0; mi < 4; ++mi) {
        float rn[4];
#pragma unroll
        for (int r = 0; r < 4; ++r) rn[r] = red_rn[wM * 64 + mi * 16 + lhi * 4 + r];
#pragma unroll
        for (int ni = 0; ni < 4; ++ni) {
#pragma unroll
            for (int r = 0; r < 4; ++r) {
                long row = m0 + wM * 64 + mi * 16 + lhi * 4 + r;
                out[row * NOUT + wN * 64 + ni * 16 + l15] = acc[mi][ni][r] * rn[r];
            }
        }
    }
}

extern "C" void kernel_launch(void* const* d_in, const int* in_sizes, int n_in,
                              void* d_out, int out_size, void* d_ws, size_t ws_size,
                              hipStream_t stream) {
    const float* x   = (const float*)d_in[0];
    const int*   ei  = (const int*)d_in[1];
    const float* cw  = (const float*)d_in[2];
    const float* cb  = (const float*)d_in[3];
    const float* f1w = (const float*)d_in[4];
    const float* f1b = (const float*)d_in[5];
    const float* f2w = (const float*)d_in[6];
    const float* f2b = (const float*)d_in[7];
    float* out = (float*)d_out;

    const int Nn  = in_sizes[0] / 2;       // nodes
    const int Bsz = Nn / NPG;              // graphs
    const int E   = in_sizes[1] / 2;       // edges
    const int* dst = ei + E;

    float*  acc2g = (float*)d_ws;                      // [NPG][Bsz] f32x2 (transposed)
    ushort* Wt    = (ushort*)(acc2g + (size_t)Nn * 2); // [28][256][32] bf16 (phase-tiled)

    const int nAgg = Bsz / 8;                          // 8192 (8 graphs per block)
    const int nTr  = (KDIM / 32) * (NOUT / 32);        // 224

    k_agg<<<nAgg + nTr, 256, 0, stream>>>(x, dst, f1w, acc2g, Wt, nAgg);
    k_gemm<<<Bsz / BM, 512, 0, stream>>>(acc2g, Wt, cw, cb, f1b, f2w, f2b, out, Bsz);
}